// Round 1
// baseline (2403.105 us; speedup 1.0000x reference)
//
#include <hip/hip_runtime.h>
#include <math.h>

#define B_ 64
#define L_ 512
#define E_ 256
#define H_ 256
#define R_ 50
#define NEG_ 1.0e10f

__device__ __forceinline__ float sigmoidf_(float x) { return 1.0f / (1.0f + expf(-x)); }
__device__ __forceinline__ float geluf_(float x) { return 0.5f * x * (1.0f + erff(x * 0.7071067811865476f)); }

// ---------------- prep input kernels ----------------
__global__ void k_prep1(const float* __restrict__ sos, float* __restrict__ inp) {
    int b = blockIdx.x, e = threadIdx.x;
    inp[b * E_ + e] = sos[e];
}
__global__ void k_prep2(const float* __restrict__ enc1, const int* __restrict__ k1,
                        const int* __restrict__ k2, float* __restrict__ inp) {
    int b = blockIdx.x, e = threadIdx.x;
    inp[b * E_ + e] = enc1[((size_t)b * L_ + k1[b]) * E_ + e] + enc1[((size_t)b * L_ + k2[b]) * E_ + e];
}
__global__ void k_prep3(const float* __restrict__ rel_emb, const int* __restrict__ rin,
                        float* __restrict__ inp) {
    int b = blockIdx.x, e = threadIdx.x;
    inp[b * E_ + e] = rel_emb[rin[b] * E_ + e];
}

// ---------------- LSTM step: one block per batch row ----------------
__global__ __launch_bounds__(256) void k_lstm(
    const float* __restrict__ inp, const float* __restrict__ h_in,
    const float* __restrict__ c_in, const float* __restrict__ W_ih,
    const float* __restrict__ W_hh, const float* __restrict__ b_ih,
    const float* __restrict__ b_hh, float* __restrict__ h_out, float* __restrict__ c_out) {
    int b = blockIdx.x, t = threadIdx.x;
    __shared__ float xs[E_], hs[H_];
    xs[t] = inp[b * E_ + t];
    hs[t] = h_in[b * H_ + t];
    __syncthreads();
    float g4[4];
#pragma unroll
    for (int g = 0; g < 4; ++g) {
        int row = g * H_ + t;
        float acc = b_ih[row] + b_hh[row];
        const float4* wi = (const float4*)&W_ih[(size_t)row * E_];
        const float4* wh = (const float4*)&W_hh[(size_t)row * H_];
        for (int k = 0; k < E_ / 4; ++k) {
            float4 a = wi[k];
            acc += a.x * xs[4 * k] + a.y * xs[4 * k + 1] + a.z * xs[4 * k + 2] + a.w * xs[4 * k + 3];
        }
        for (int k = 0; k < H_ / 4; ++k) {
            float4 a = wh[k];
            acc += a.x * hs[4 * k] + a.y * hs[4 * k + 1] + a.z * hs[4 * k + 2] + a.w * hs[4 * k + 3];
        }
        g4[g] = acc;
    }
    float ig = sigmoidf_(g4[0]), fg = sigmoidf_(g4[1]);
    float gg = tanhf(g4[2]), og = sigmoidf_(g4[3]);
    float cn = fg * c_in[b * H_ + t] + ig * gg;
    float hn = og * tanhf(cn);
    __syncthreads();
    h_out[b * H_ + t] = hn;
    c_out[b * H_ + t] = cn;
}

// ---------------- attention: scores + softmax + mix, one block per b ----------------
__global__ __launch_bounds__(512) void k_attn(
    const float* __restrict__ h, const float* __restrict__ enc, float* __restrict__ mix) {
    int b = blockIdx.x, t = threadIdx.x;
    __shared__ float hs[E_];
    __shared__ float sc[L_];
    __shared__ float red[8];
    __shared__ float mixs[2][E_];
    if (t < E_) hs[t] = h[b * E_ + t];
    __syncthreads();
    // scores[l] = h . enc[b,l,:]
    {
        const float4* row = (const float4*)&enc[((size_t)b * L_ + t) * E_];
        float acc = 0.f;
        for (int k = 0; k < E_ / 4; ++k) {
            float4 a = row[k];
            acc += a.x * hs[4 * k] + a.y * hs[4 * k + 1] + a.z * hs[4 * k + 2] + a.w * hs[4 * k + 3];
        }
        sc[t] = acc;
    }
    __syncthreads();
    // max
    float v = sc[t];
#pragma unroll
    for (int off = 32; off; off >>= 1) v = fmaxf(v, __shfl_xor(v, off));
    if ((t & 63) == 0) red[t >> 6] = v;
    __syncthreads();
    float m = red[0];
#pragma unroll
    for (int i = 1; i < 8; ++i) m = fmaxf(m, red[i]);
    float ev = expf(sc[t] - m);
    __syncthreads();
    v = ev;
#pragma unroll
    for (int off = 32; off; off >>= 1) v += __shfl_xor(v, off);
    if ((t & 63) == 0) red[t >> 6] = v;
    __syncthreads();
    float s = 0.f;
#pragma unroll
    for (int i = 0; i < 8; ++i) s += red[i];
    sc[t] = ev / s;
    __syncthreads();
    // mix[e] = sum_l attn[l]*enc[b,l,e]; split l-range over two halves of the block
    {
        int e = t & (E_ - 1), half = t >> 8;
        float acc = 0.f;
        const float* base = &enc[((size_t)b * L_ + half * 256) * E_ + e];
        for (int l = 0; l < 256; ++l) acc += sc[half * 256 + l] * base[(size_t)l * E_];
        mixs[half][e] = acc;
    }
    __syncthreads();
    if (t < E_) mix[b * E_ + t] = mixs[0][t] + mixs[1][t];
}

// ---------------- out = tanh([mix,h] @ W_attn^T + b_attn) ----------------
__global__ __launch_bounds__(256) void k_attnout(
    const float* __restrict__ mix, const float* __restrict__ h,
    const float* __restrict__ W_attn, const float* __restrict__ b_attn,
    float* __restrict__ aout) {
    int b = blockIdx.x, t = threadIdx.x;
    __shared__ float cat[2 * E_];
    cat[t] = mix[b * E_ + t];
    cat[E_ + t] = h[b * E_ + t];
    __syncthreads();
    const float4* w = (const float4*)&W_attn[(size_t)t * 2 * E_];
    float acc = 0.f;
    for (int k = 0; k < 2 * E_ / 4; ++k) {
        float4 a = w[k];
        acc += a.x * cat[4 * k] + a.y * cat[4 * k + 1] + a.z * cat[4 * k + 2] + a.w * cat[4 * k + 3];
    }
    aout[b * E_ + t] = tanhf(acc + b_attn[t]);
}

// ---------------- per-(b,o) contribution of broadcast 'out' through the conv ----------------
__global__ __launch_bounds__(256) void k_ocontrib(
    const float* __restrict__ aout, const float* __restrict__ w, // (E, 512, 3)
    float* __restrict__ fullv, float* __restrict__ corr0, float* __restrict__ corr2) {
    int b = blockIdx.x, o = threadIdx.x;
    __shared__ float os[E_];
    os[o] = aout[b * E_ + o];
    __syncthreads();
    const float* wr = &w[(size_t)o * 1536 + 768]; // c = 256..511
    float f = 0.f, a0 = 0.f, a2 = 0.f;
    for (int c = 0; c < E_; ++c) {
        float w0 = wr[c * 3 + 0], w1 = wr[c * 3 + 1], w2 = wr[c * 3 + 2];
        float vv = os[c];
        f += vv * (w0 + w1 + w2);
        a0 += vv * w0;
        a2 += vv * w2;
    }
    fullv[b * E_ + o] = f;
    corr0[b * E_ + o] = a0;
    corr2[b * E_ + o] = a2;
}

// ---------------- weight transpose: wT[k][c][o] = w[o][c][k], c<256 ----------------
__global__ void k_transw(const float* __restrict__ w, float* __restrict__ wT) {
    int idx = blockIdx.x * 256 + threadIdx.x; // 3*256*256 = 196608
    if (idx >= 3 * E_ * E_) return;
    int o = idx & 255, c = (idx >> 8) & 255, k = idx >> 16;
    wT[idx] = w[(size_t)o * 1536 + c * 3 + k];
}

// ---------------- conv GEMM: out[b,l,o] = sum_k sum_c enc[b,l+k-1,c]*w[o,c,k] + bias + out-part ----------------
#define BM 64
#define BN 64
#define BK 16
__global__ __launch_bounds__(256) void k_conv(
    const float* __restrict__ enc, const float* __restrict__ wT, // [3][256][256]
    const float* __restrict__ bias, const float* __restrict__ fullv,
    const float* __restrict__ corr0, const float* __restrict__ corr2,
    float* __restrict__ out) {
    const int b = blockIdx.z;
    const int l0 = blockIdx.y * BM;
    const int o0 = blockIdx.x * BN;
    const int tid = threadIdx.x;

    __shared__ float At[BK][68];      // [c][x], x = l - l0 + 1, x in [0,66)
    __shared__ float Bt[BK][3][BN];   // [c][k][o]

    float acc[4][4] = {{0.f}};
    const int lr = (tid >> 4) << 2; // 0..60
    const int oc = (tid & 15) << 2; // 0..60
    const int ac = tid & 15;        // c for A staging
    const int ax = tid >> 4;        // x base for A staging

    for (int c0 = 0; c0 < E_; c0 += BK) {
        __syncthreads();
        // stage A window (zero-padded at sequence edges)
        for (int x = ax; x < 66; x += 16) {
            int l = l0 - 1 + x;
            float v = 0.f;
            if (l >= 0 && l < L_) v = enc[((size_t)b * L_ + l) * E_ + c0 + ac];
            At[ac][x] = v;
        }
        // stage B (coalesced from pre-transposed weights)
        for (int idx = tid; idx < BK * 3 * BN; idx += 256) {
            int o = idx & 63;
            int c = (idx >> 6) & 15;
            int k = idx >> 10;
            Bt[c][k][o] = wT[((size_t)k * E_ + c0 + c) * E_ + o0 + o];
        }
        __syncthreads();
#pragma unroll
        for (int c = 0; c < BK; ++c) {
            float4 w0 = *(const float4*)&At[c][lr];
            float2 w1 = *(const float2*)&At[c][lr + 4];
            float win[6] = {w0.x, w0.y, w0.z, w0.w, w1.x, w1.y};
            float4 bv0 = *(const float4*)&Bt[c][0][oc];
            float4 bv1 = *(const float4*)&Bt[c][1][oc];
            float4 bv2 = *(const float4*)&Bt[c][2][oc];
#pragma unroll
            for (int i = 0; i < 4; ++i) {
                acc[i][0] += win[i] * bv0.x + win[i + 1] * bv1.x + win[i + 2] * bv2.x;
                acc[i][1] += win[i] * bv0.y + win[i + 1] * bv1.y + win[i + 2] * bv2.y;
                acc[i][2] += win[i] * bv0.z + win[i + 1] * bv1.z + win[i + 2] * bv2.z;
                acc[i][3] += win[i] * bv0.w + win[i + 1] * bv1.w + win[i + 2] * bv2.w;
            }
        }
    }
#pragma unroll
    for (int i = 0; i < 4; ++i) {
        int l = l0 + lr + i;
        float4 v4;
        float* vp = (float*)&v4;
#pragma unroll
        for (int j = 0; j < 4; ++j) {
            int o = o0 + oc + j;
            float v = acc[i][j] + bias[o] + fullv[b * E_ + o];
            if (l == 0) v -= corr0[b * E_ + o];
            if (l == L_ - 1) v -= corr2[b * E_ + o];
            vp[j] = v;
        }
        *(float4*)&out[((size_t)b * L_ + l) * E_ + o0 + oc] = v4;
    }
}

// ---------------- entity heads: one wave per (b,l) row, gelu fused ----------------
__global__ __launch_bounds__(256) void k_heads(
    const float* __restrict__ enc, const float* __restrict__ w1, const float* __restrict__ b1,
    const float* __restrict__ w2, const float* __restrict__ b2,
    float* __restrict__ o1, float* __restrict__ o2) {
    int gl = blockIdx.x * 4 + (threadIdx.x >> 6); // b*L + l
    int lane = threadIdx.x & 63;
    float4 x = *(const float4*)&enc[(size_t)gl * E_ + lane * 4];
    float g0 = geluf_(x.x), g1 = geluf_(x.y), g2 = geluf_(x.z), g3 = geluf_(x.w);
    float4 a = *(const float4*)&w1[lane * 4];
    float4 bb = *(const float4*)&w2[lane * 4];
    float p1 = g0 * a.x + g1 * a.y + g2 * a.z + g3 * a.w;
    float p2 = g0 * bb.x + g1 * bb.y + g2 * bb.z + g3 * bb.w;
#pragma unroll
    for (int off = 32; off; off >>= 1) {
        p1 += __shfl_xor(p1, off);
        p2 += __shfl_xor(p2, off);
    }
    if (lane == 0) {
        o1[gl] = p1 + b1[0];
        o2[gl] = p2 + b2[0];
    }
}

// ---------------- relation head: masked max over l, partial per 64-l chunk ----------------
__global__ __launch_bounds__(256) void k_relmax_part(
    const float* __restrict__ enc, const float* __restrict__ W_rel,
    const float* __restrict__ b_rel, const int* __restrict__ T,
    float* __restrict__ pmax) { // (B, 8, 64)
    int b = blockIdx.y, chunk = blockIdx.x, t = threadIdx.x;
    int r = t & 63, seg = t >> 6;
    __shared__ float as[E_];
    __shared__ float pm[4][64];
    __shared__ float rmax[64];
    if (t < 64) rmax[t] = -3.0e38f;
    for (int li = 0; li < 64; ++li) {
        int l = chunk * 64 + li;
        __syncthreads();
        as[t] = geluf_(enc[((size_t)b * L_ + l) * E_ + t]);
        __syncthreads();
        float p = 0.f;
        if (r < R_) {
            const float4* wr = (const float4*)&W_rel[(size_t)r * E_ + seg * 64];
            const float* av = &as[seg * 64];
            for (int k = 0; k < 16; ++k) {
                float4 a = wr[k];
                p += a.x * av[4 * k] + a.y * av[4 * k + 1] + a.z * av[4 * k + 2] + a.w * av[4 * k + 3];
            }
        }
        pm[seg][r] = p;
        __syncthreads();
        if (t < 64) {
            float logit = pm[0][t] + pm[1][t] + pm[2][t] + pm[3][t] + ((t < R_) ? b_rel[t] : 0.f);
            float msk = (T[b * L_ + l] > 0) ? 0.f : NEG_;
            rmax[t] = fmaxf(rmax[t], logit - msk);
        }
    }
    __syncthreads();
    if (t < 64) pmax[((size_t)b * 8 + chunk) * 64 + t] = rmax[t];
}

__global__ void k_relmax_red(const float* __restrict__ pmax, float* __restrict__ t2rel) {
    int b = blockIdx.x, r = threadIdx.x;
    if (r >= R_) return;
    float m = -3.0e38f;
    for (int ch = 0; ch < 8; ++ch) m = fmaxf(m, pmax[((size_t)b * 8 + ch) * 64 + r]);
    t2rel[b * R_ + r] = m;
}

// ---------------- driver ----------------
extern "C" void kernel_launch(void* const* d_in, const int* in_sizes, int n_in,
                              void* d_out, int out_size, void* d_ws, size_t ws_size,
                              hipStream_t stream) {
    const float* encoder_o = (const float*)d_in[0];
    const float* h0 = (const float*)d_in[1];
    const float* c0 = (const float*)d_in[2];
    const float* sos_emb = (const float*)d_in[3];
    const float* rel_emb = (const float*)d_in[4];
    const float* W_ih = (const float*)d_in[5];
    const float* W_hh = (const float*)d_in[6];
    const float* b_ih = (const float*)d_in[7];
    const float* b_hh = (const float*)d_in[8];
    const float* W_attn = (const float*)d_in[9];
    const float* b_attn = (const float*)d_in[10];
    const float* conv_rel_w = (const float*)d_in[11];
    const float* conv_rel_b = (const float*)d_in[12];
    const float* conv_ent_w = (const float*)d_in[13];
    const float* conv_ent_b = (const float*)d_in[14];
    const float* W_rel = (const float*)d_in[15];
    const float* b_rel = (const float*)d_in[16];
    const float* w_e1 = (const float*)d_in[17];
    const float* b_e1 = (const float*)d_in[18];
    const float* w_e2 = (const float*)d_in[19];
    const float* b_e2 = (const float*)d_in[20];
    const int* T = (const int*)d_in[21];
    const int* R_in = (const int*)d_in[22];
    const int* S_K1 = (const int*)d_in[23];
    const int* S_K2 = (const int*)d_in[24];

    float* out = (float*)d_out;
    float* t1e1 = out;
    float* t1e2 = out + 32768;
    float* t2rel = out + 65536;
    float* t3e1 = out + 68736;
    float* t3e2 = out + 101504;

    float* ws = (float*)d_ws;
    size_t off = 0;
    float* encA = ws + off; off += (size_t)B_ * L_ * E_;
    float* encB = ws + off; off += (size_t)B_ * L_ * E_;
    float* hbuf = ws + off; off += B_ * H_;
    float* cbuf = ws + off; off += B_ * H_;
    float* inp  = ws + off; off += B_ * E_;
    float* mixb = ws + off; off += B_ * E_;
    float* aout = ws + off; off += B_ * E_;
    float* fullv = ws + off; off += B_ * E_;
    float* cr0  = ws + off; off += B_ * E_;
    float* cr2  = ws + off; off += B_ * E_;
    float* pmax = ws + off; off += B_ * 8 * 64;
    float* wTe  = ws + off; off += 3 * E_ * E_;
    float* wTr  = ws + off; off += 3 * E_ * E_;

    dim3 convGrid(E_ / BN, L_ / BM, B_);

    k_transw<<<768, 256, 0, stream>>>(conv_ent_w, wTe);
    k_transw<<<768, 256, 0, stream>>>(conv_rel_w, wTr);

    // ---- step 1: sos -> entity heads ----
    k_prep1<<<B_, 256, 0, stream>>>(sos_emb, inp);
    k_lstm<<<B_, 256, 0, stream>>>(inp, h0, c0, W_ih, W_hh, b_ih, b_hh, hbuf, cbuf);
    k_attn<<<B_, 512, 0, stream>>>(hbuf, encoder_o, mixb);
    k_attnout<<<B_, 256, 0, stream>>>(mixb, hbuf, W_attn, b_attn, aout);
    k_ocontrib<<<B_, 256, 0, stream>>>(aout, conv_ent_w, fullv, cr0, cr2);
    k_conv<<<convGrid, 256, 0, stream>>>(encoder_o, wTe, conv_ent_b, fullv, cr0, cr2, encA);
    k_heads<<<B_ * L_ / 4, 256, 0, stream>>>(encA, w_e1, b_e1, w_e2, b_e2, t1e1, t1e2);

    // ---- step 2: gathered entity spans -> relation logits ----
    k_prep2<<<B_, 256, 0, stream>>>(encA, S_K1, S_K2, inp);
    k_lstm<<<B_, 256, 0, stream>>>(inp, hbuf, cbuf, W_ih, W_hh, b_ih, b_hh, hbuf, cbuf);
    k_attn<<<B_, 512, 0, stream>>>(hbuf, encA, mixb);
    k_attnout<<<B_, 256, 0, stream>>>(mixb, hbuf, W_attn, b_attn, aout);
    k_ocontrib<<<B_, 256, 0, stream>>>(aout, conv_rel_w, fullv, cr0, cr2);
    k_conv<<<convGrid, 256, 0, stream>>>(encA, wTr, conv_rel_b, fullv, cr0, cr2, encB);
    {
        dim3 rmGrid(8, B_);
        k_relmax_part<<<rmGrid, 256, 0, stream>>>(encB, W_rel, b_rel, T, pmax);
        k_relmax_red<<<B_, 64, 0, stream>>>(pmax, t2rel);
    }

    // ---- step 3: relation embedding -> entity heads ----
    k_prep3<<<B_, 256, 0, stream>>>(rel_emb, R_in, inp);
    k_lstm<<<B_, 256, 0, stream>>>(inp, hbuf, cbuf, W_ih, W_hh, b_ih, b_hh, hbuf, cbuf);
    k_attn<<<B_, 512, 0, stream>>>(hbuf, encB, mixb);
    k_attnout<<<B_, 256, 0, stream>>>(mixb, hbuf, W_attn, b_attn, aout);
    k_ocontrib<<<B_, 256, 0, stream>>>(aout, conv_ent_w, fullv, cr0, cr2);
    k_conv<<<convGrid, 256, 0, stream>>>(encB, wTe, conv_ent_b, fullv, cr0, cr2, encA);
    k_heads<<<B_ * L_ / 4, 256, 0, stream>>>(encA, w_e1, b_e1, w_e2, b_e2, t3e1, t3e2);
}

// Round 2
// 448.881 us; speedup vs baseline: 5.3535x; 5.3535x over previous
//
#include <hip/hip_runtime.h>
#include <math.h>

#define B_ 64
#define L_ 512
#define E_ 256
#define H_ 256
#define R_ 50
#define NEG_ 1.0e10f

typedef __bf16 bf16x8 __attribute__((ext_vector_type(8)));
typedef float f32x4 __attribute__((ext_vector_type(4)));

__device__ __forceinline__ float sigmoidf_(float x) { return 1.0f / (1.0f + expf(-x)); }
__device__ __forceinline__ float geluf_(float x) { return 0.5f * x * (1.0f + erff(x * 0.7071067811865476f)); }
__device__ __forceinline__ unsigned short f2bf(float x) {
    unsigned u = __float_as_uint(x);
    return (unsigned short)((u + 0x7fffu + ((u >> 16) & 1u)) >> 16);
}

// ---------------- prep input kernels ----------------
__global__ void k_prep1(const float* __restrict__ sos, float* __restrict__ inp) {
    int b = blockIdx.x, e = threadIdx.x;
    inp[b * E_ + e] = sos[e];
}
__global__ void k_prep2(const float* __restrict__ enc1, const int* __restrict__ k1,
                        const int* __restrict__ k2, float* __restrict__ inp) {
    int b = blockIdx.x, e = threadIdx.x;
    inp[b * E_ + e] = enc1[((size_t)b * L_ + k1[b]) * E_ + e] + enc1[((size_t)b * L_ + k2[b]) * E_ + e];
}
__global__ void k_prep3(const float* __restrict__ rel_emb, const int* __restrict__ rin,
                        float* __restrict__ inp) {
    int b = blockIdx.x, e = threadIdx.x;
    inp[b * E_ + e] = rel_emb[rin[b] * E_ + e];
}

// ---------------- LSTM as tiled GEMM: gates(64,1024) = [inp|h](64,512) @ [W_ih|W_hh]^T ----------------
__global__ __launch_bounds__(256) void k_lstm_gemm(
    const float* __restrict__ inp, const float* __restrict__ h,
    const float* __restrict__ W_ih, const float* __restrict__ W_hh,
    float* __restrict__ gates) {
    const int g0 = blockIdx.x * 64;
    const int t = threadIdx.x;
    const int tx = t & 15, ty = t >> 4;
    __shared__ float Xs[64][68];
    __shared__ float Wt[64][68];
    float acc[4][4] = {{0.f}};
    for (int k0 = 0; k0 < 512; k0 += 64) {
        const float* Xsrc = (k0 < 256) ? inp : h;
        const float* Wsrc = (k0 < 256) ? W_ih : W_hh;
        const int kb = k0 & 255;
        __syncthreads();
#pragma unroll
        for (int i = 0; i < 4; ++i) {
            int idx = i * 256 + t;
            int row = idx >> 4, kk = (idx & 15) << 2;
            *(float4*)&Xs[row][kk] = *(const float4*)&Xsrc[row * 256 + kb + kk];
            *(float4*)&Wt[row][kk] = *(const float4*)&Wsrc[(size_t)(g0 + row) * 256 + kb + kk];
        }
        __syncthreads();
#pragma unroll
        for (int kk = 0; kk < 64; kk += 4) {
            float4 xv[4], wv[4];
#pragma unroll
            for (int i = 0; i < 4; ++i) xv[i] = *(const float4*)&Xs[ty * 4 + i][kk];
#pragma unroll
            for (int j = 0; j < 4; ++j) wv[j] = *(const float4*)&Wt[tx * 4 + j][kk];
#pragma unroll
            for (int i = 0; i < 4; ++i)
#pragma unroll
                for (int j = 0; j < 4; ++j)
                    acc[i][j] += xv[i].x * wv[j].x + xv[i].y * wv[j].y + xv[i].z * wv[j].z + xv[i].w * wv[j].w;
        }
    }
#pragma unroll
    for (int i = 0; i < 4; ++i)
#pragma unroll
        for (int j = 0; j < 4; ++j)
            gates[(size_t)(ty * 4 + i) * 1024 + g0 + tx * 4 + j] = acc[i][j];
}

__global__ void k_lstm_fin(const float* __restrict__ gates, const float* __restrict__ b_ih,
                           const float* __restrict__ b_hh, const float* __restrict__ c_in,
                           float* __restrict__ h_out, float* __restrict__ c_out) {
    int b = blockIdx.x, t = threadIdx.x;
    size_t base = (size_t)b * 1024;
    float gi = gates[base + t] + b_ih[t] + b_hh[t];
    float gf = gates[base + 256 + t] + b_ih[256 + t] + b_hh[256 + t];
    float gg = gates[base + 512 + t] + b_ih[512 + t] + b_hh[512 + t];
    float go = gates[base + 768 + t] + b_ih[768 + t] + b_hh[768 + t];
    float c = sigmoidf_(gf) * c_in[b * H_ + t] + sigmoidf_(gi) * tanhf(gg);
    float hv = sigmoidf_(go) * tanhf(c);
    h_out[b * H_ + t] = hv;
    c_out[b * H_ + t] = c;
}

// ---------------- attention, chunked flash-style ----------------
__global__ __launch_bounds__(256) void k_attn_part(
    const float* __restrict__ h, const float* __restrict__ enc,
    float* __restrict__ mixp, float* __restrict__ stats) {
    int b = blockIdx.y, ch = blockIdx.x, t = threadIdx.x;
    __shared__ float hs[E_];
    __shared__ float sc[128];
    __shared__ float red[4], red2[4];
    hs[t] = h[b * E_ + t];
    __syncthreads();
    if (t < 128) {
        const float4* row = (const float4*)&enc[((size_t)b * L_ + ch * 128 + t) * E_];
        float acc = 0.f;
        for (int k = 0; k < E_ / 4; ++k) {
            float4 a = row[k];
            acc += a.x * hs[4 * k] + a.y * hs[4 * k + 1] + a.z * hs[4 * k + 2] + a.w * hs[4 * k + 3];
        }
        sc[t] = acc;
    }
    __syncthreads();
    float v = (t < 128) ? sc[t] : -3.0e38f;
#pragma unroll
    for (int off = 32; off; off >>= 1) v = fmaxf(v, __shfl_xor(v, off));
    if ((t & 63) == 0) red[t >> 6] = v;
    __syncthreads();
    float m = fmaxf(fmaxf(red[0], red[1]), fmaxf(red[2], red[3]));
    float ev = (t < 128) ? expf(sc[t] - m) : 0.f;
    float sv = ev;
#pragma unroll
    for (int off = 32; off; off >>= 1) sv += __shfl_xor(sv, off);
    if ((t & 63) == 0) red2[t >> 6] = sv;
    if (t < 128) sc[t] = ev;
    __syncthreads();
    float s = red2[0] + red2[1] + red2[2] + red2[3];
    // mix partial over this chunk's 128 positions
    float acc = 0.f;
    const float* base = &enc[((size_t)b * L_ + ch * 128) * E_ + t];
#pragma unroll 4
    for (int l = 0; l < 128; ++l) acc += sc[l] * base[(size_t)l * E_];
    mixp[((size_t)b * 4 + ch) * E_ + t] = acc;
    if (t == 0) {
        stats[((size_t)b * 4 + ch) * 2] = m;
        stats[((size_t)b * 4 + ch) * 2 + 1] = s;
    }
}

__global__ __launch_bounds__(256) void k_attn_comb(
    const float* __restrict__ mixp, const float* __restrict__ stats,
    const float* __restrict__ h, const float* __restrict__ W_attn,
    const float* __restrict__ b_attn, float* __restrict__ aout) {
    int b = blockIdx.x, t = threadIdx.x;
    __shared__ float cat[2 * E_];
    float m0 = stats[(b * 4 + 0) * 2], m1 = stats[(b * 4 + 1) * 2];
    float m2 = stats[(b * 4 + 2) * 2], m3 = stats[(b * 4 + 3) * 2];
    float M = fmaxf(fmaxf(m0, m1), fmaxf(m2, m3));
    float w0 = expf(m0 - M), w1 = expf(m1 - M), w2 = expf(m2 - M), w3 = expf(m3 - M);
    float denom = stats[(b * 4 + 0) * 2 + 1] * w0 + stats[(b * 4 + 1) * 2 + 1] * w1 +
                  stats[(b * 4 + 2) * 2 + 1] * w2 + stats[(b * 4 + 3) * 2 + 1] * w3;
    float mixv = (mixp[((size_t)b * 4 + 0) * E_ + t] * w0 + mixp[((size_t)b * 4 + 1) * E_ + t] * w1 +
                  mixp[((size_t)b * 4 + 2) * E_ + t] * w2 + mixp[((size_t)b * 4 + 3) * E_ + t] * w3) / denom;
    cat[t] = mixv;
    cat[E_ + t] = h[b * E_ + t];
    __syncthreads();
    const float4* w = (const float4*)&W_attn[(size_t)t * 2 * E_];
    float acc = 0.f;
    for (int k = 0; k < 2 * E_ / 4; ++k) {
        float4 a = w[k];
        acc += a.x * cat[4 * k] + a.y * cat[4 * k + 1] + a.z * cat[4 * k + 2] + a.w * cat[4 * k + 3];
    }
    aout[b * E_ + t] = tanhf(acc + b_attn[t]);
}

// ---------------- per-(b,o) contribution of broadcast 'out' through the conv ----------------
__global__ __launch_bounds__(256) void k_ocontrib(
    const float* __restrict__ aout, const float* __restrict__ w, // (E, 512, 3)
    float* __restrict__ fullv, float* __restrict__ corr0, float* __restrict__ corr2) {
    int b = blockIdx.x, o = threadIdx.x;
    __shared__ float os[E_];
    os[o] = aout[b * E_ + o];
    __syncthreads();
    const float* wr = &w[(size_t)o * 1536 + 768]; // c = 256..511
    float f = 0.f, a0 = 0.f, a2 = 0.f;
    for (int c = 0; c < E_; ++c) {
        float w0 = wr[c * 3 + 0], w1 = wr[c * 3 + 1], w2 = wr[c * 3 + 2];
        float vv = os[c];
        f += vv * (w0 + w1 + w2);
        a0 += vv * w0;
        a2 += vv * w2;
    }
    fullv[b * E_ + o] = f;
    corr0[b * E_ + o] = a0;
    corr2[b * E_ + o] = a2;
}

// ---------------- pack conv weights (c<256 part) into bf16 MFMA B-fragment order ----------------
// Bpack[of][kc][lane][8]: of=o-frag (16 o's), kc=K-chunk (K=(tap k)*256+c), lane frag mapping:
// col o = of*16 + (lane&15), k_in_chunk = (lane>>4)*8 + j
__global__ void k_packB(const float* __restrict__ w, unsigned short* __restrict__ bp) {
    int idx = blockIdx.x * 256 + threadIdx.x; // < 16*24*64
    if (idx >= 16 * 24 * 64) return;
    int l = idx & 63, kc = (idx >> 6) % 24, of = idx / (24 * 64);
    int o = of * 16 + (l & 15);
    int k = kc >> 3;
    int cb = ((kc & 7) << 5) + ((l >> 4) << 3);
    unsigned short v[8];
#pragma unroll
    for (int j = 0; j < 8; ++j) v[j] = f2bf(w[(size_t)o * 1536 + (size_t)(cb + j) * 3 + k]);
    unsigned int* dst = (unsigned int*)&bp[(size_t)idx * 8];
#pragma unroll
    for (int j = 0; j < 4; ++j) dst[j] = (unsigned int)v[2 * j] | ((unsigned int)v[2 * j + 1] << 16);
}

// pack W_rel (50x256, pad N to 64) into B-fragment order: Wpack[of(4)][kc(8)][lane][8]
__global__ void k_packW(const float* __restrict__ W_rel, unsigned short* __restrict__ wp) {
    int idx = blockIdx.x * 256 + threadIdx.x; // < 4*8*64
    if (idx >= 4 * 8 * 64) return;
    int l = idx & 63, kc = (idx >> 6) & 7, of = idx / (8 * 64);
    int r = of * 16 + (l & 15);
    int k = kc * 32 + ((l >> 4) << 3);
    unsigned short v[8];
#pragma unroll
    for (int j = 0; j < 8; ++j) v[j] = (r < R_) ? f2bf(W_rel[(size_t)r * E_ + k + j]) : 0;
    unsigned int* dst = (unsigned int*)&wp[(size_t)idx * 8];
#pragma unroll
    for (int j = 0; j < 4; ++j) dst[j] = (unsigned int)v[2 * j] | ((unsigned int)v[2 * j + 1] << 16);
}

// ---------------- conv as bf16 MFMA GEMM ----------------
// out[b,l,o] = sum_{k,c} enc[b,l+k-1,c] * w[o,c,k] + bias[o] + fullv[b,o] (- edge corr)
__global__ __launch_bounds__(256) void k_conv_mfma(
    const float* __restrict__ enc, const unsigned short* __restrict__ bp,
    const float* __restrict__ bias, const float* __restrict__ fullv,
    const float* __restrict__ cr0, const float* __restrict__ cr2,
    float* __restrict__ out) {
    const int b = blockIdx.z, l0 = blockIdx.y * 64, o0g = blockIdx.x;
    const int t = threadIdx.x, lane = t & 63, wid = t >> 6;
    __shared__ unsigned short As[66 * 256]; // XOR-swizzled bf16, row r = enc row l0-1+r

    // stage A (f32 -> bf16, zero-padded halo)
#pragma unroll
    for (int i = 0; i < 17; ++i) {
        int idx = i * 256 + t;
        if (idx < 66 * 64) {
            int row = idx >> 6, c = (idx & 63) << 2;
            int l = l0 - 1 + row;
            float4 v = {0.f, 0.f, 0.f, 0.f};
            if (l >= 0 && l < L_) v = *(const float4*)&enc[((size_t)b * L_ + l) * E_ + c];
            uint2 p;
            p.x = (unsigned int)f2bf(v.x) | ((unsigned int)f2bf(v.y) << 16);
            p.y = (unsigned int)f2bf(v.z) | ((unsigned int)f2bf(v.w) << 16);
            int ea = (row << 8) + ((((c >> 3) ^ (row & 7))) << 3) + (c & 7);
            *(uint2*)&As[ea] = p;
        }
    }
    __syncthreads();

    const int wl = (wid >> 1) << 5;      // wave l-offset (0 or 32)
    const int wof = (wid & 1) << 1;      // wave o-frag offset (0 or 2), in 16-o units
    f32x4 zero = {0.f, 0.f, 0.f, 0.f};
    f32x4 acc[2][2] = {{zero, zero}, {zero, zero}};
    const int arow_base = wl + (lane & 15);
    const int agrp = lane >> 4;
    const int ofg = o0g * 4 + wof;

#pragma unroll 4
    for (int kc = 0; kc < 24; ++kc) {
        const int k = kc >> 3;
        const int g = ((kc & 7) << 2) + agrp;
        const int r0 = arow_base + k;
        const int r1 = r0 + 16;
        bf16x8 a0 = *(const bf16x8*)&As[(r0 << 8) + ((g ^ (r0 & 7)) << 3)];
        bf16x8 a1 = *(const bf16x8*)&As[(r1 << 8) + ((g ^ (r1 & 7)) << 3)];
        bf16x8 b0 = *(const bf16x8*)&bp[(((size_t)ofg * 24 + kc) * 64 + lane) * 8];
        bf16x8 b1 = *(const bf16x8*)&bp[(((size_t)(ofg + 1) * 24 + kc) * 64 + lane) * 8];
        acc[0][0] = __builtin_amdgcn_mfma_f32_16x16x32_bf16(a0, b0, acc[0][0], 0, 0, 0);
        acc[0][1] = __builtin_amdgcn_mfma_f32_16x16x32_bf16(a0, b1, acc[0][1], 0, 0, 0);
        acc[1][0] = __builtin_amdgcn_mfma_f32_16x16x32_bf16(a1, b0, acc[1][0], 0, 0, 0);
        acc[1][1] = __builtin_amdgcn_mfma_f32_16x16x32_bf16(a1, b1, acc[1][1], 0, 0, 0);
    }

    // epilogue: C/D mapping col=lane&15, row=(lane>>4)*4+reg
    const int rbase = l0 + wl + ((lane >> 4) << 2);
#pragma unroll
    for (int ni = 0; ni < 2; ++ni) {
        int o = (ofg + ni) * 16 + (lane & 15);
        float bia = bias[o] + fullv[b * E_ + o];
        float c0v = cr0[b * E_ + o], c2v = cr2[b * E_ + o];
#pragma unroll
        for (int mi = 0; mi < 2; ++mi) {
#pragma unroll
            for (int r = 0; r < 4; ++r) {
                int lrow = rbase + mi * 16 + r;
                float v = acc[mi][ni][r] + bia;
                if (lrow == 0) v -= c0v;
                if (lrow == L_ - 1) v -= c2v;
                out[((size_t)b * L_ + lrow) * E_ + o] = v;
            }
        }
    }
}

// ---------------- entity heads: one wave per (b,l) row, gelu fused ----------------
__global__ __launch_bounds__(256) void k_heads(
    const float* __restrict__ enc, const float* __restrict__ w1, const float* __restrict__ b1,
    const float* __restrict__ w2, const float* __restrict__ b2,
    float* __restrict__ o1, float* __restrict__ o2) {
    int gl = blockIdx.x * 4 + (threadIdx.x >> 6);
    int lane = threadIdx.x & 63;
    float4 x = *(const float4*)&enc[(size_t)gl * E_ + lane * 4];
    float g0 = geluf_(x.x), g1 = geluf_(x.y), g2 = geluf_(x.z), g3 = geluf_(x.w);
    float4 a = *(const float4*)&w1[lane * 4];
    float4 bb = *(const float4*)&w2[lane * 4];
    float p1 = g0 * a.x + g1 * a.y + g2 * a.z + g3 * a.w;
    float p2 = g0 * bb.x + g1 * bb.y + g2 * bb.z + g3 * bb.w;
#pragma unroll
    for (int off = 32; off; off >>= 1) {
        p1 += __shfl_xor(p1, off);
        p2 += __shfl_xor(p2, off);
    }
    if (lane == 0) {
        o1[gl] = p1 + b1[0];
        o2[gl] = p2 + b2[0];
    }
}

// ---------------- relation head: MFMA gelu(enc) @ W_rel^T with masked-max epilogue ----------------
__global__ __launch_bounds__(256) void k_relmax_mfma(
    const float* __restrict__ enc, const unsigned short* __restrict__ wp,
    const float* __restrict__ b_rel, const int* __restrict__ T,
    float* __restrict__ pmax) { // (B, 8, 64)
    const int b = blockIdx.y, l0 = blockIdx.x * 64;
    const int t = threadIdx.x, lane = t & 63, wid = t >> 6;
    __shared__ unsigned short As[64 * 256];
    __shared__ int Tm[64];
    __shared__ float pm[4][64];

    if (t < 64) Tm[t] = T[b * L_ + l0 + t];
#pragma unroll
    for (int i = 0; i < 16; ++i) {
        int idx = i * 256 + t;
        int row = idx >> 6, c = (idx & 63) << 2;
        float4 v = *(const float4*)&enc[((size_t)b * L_ + l0 + row) * E_ + c];
        uint2 p;
        p.x = (unsigned int)f2bf(geluf_(v.x)) | ((unsigned int)f2bf(geluf_(v.y)) << 16);
        p.y = (unsigned int)f2bf(geluf_(v.z)) | ((unsigned int)f2bf(geluf_(v.w)) << 16);
        int ea = (row << 8) + ((((c >> 3) ^ (row & 7))) << 3) + (c & 7);
        *(uint2*)&As[ea] = p;
    }
    __syncthreads();

    f32x4 zero = {0.f, 0.f, 0.f, 0.f};
    f32x4 acc[4] = {zero, zero, zero, zero};
    const int arow = wid * 16 + (lane & 15);
    const int agrp = lane >> 4;
#pragma unroll 2
    for (int kc = 0; kc < 8; ++kc) {
        int g = (kc << 2) + agrp;
        bf16x8 a0 = *(const bf16x8*)&As[(arow << 8) + ((g ^ (arow & 7)) << 3)];
#pragma unroll
        for (int ni = 0; ni < 4; ++ni) {
            bf16x8 bv = *(const bf16x8*)&wp[(((size_t)ni * 8 + kc) * 64 + lane) * 8];
            acc[ni] = __builtin_amdgcn_mfma_f32_16x16x32_bf16(a0, bv, acc[ni], 0, 0, 0);
        }
    }

    const int lloc_base = wid * 16 + ((lane >> 4) << 2);
#pragma unroll
    for (int ni = 0; ni < 4; ++ni) {
        int r = ni * 16 + (lane & 15);
        float brel = (r < R_) ? b_rel[r] : 0.f;
        float v = -3.0e38f;
#pragma unroll
        for (int rg = 0; rg < 4; ++rg) {
            float logit = acc[ni][rg] + brel;
            float pen = (Tm[lloc_base + rg] > 0) ? 0.f : NEG_;
            v = fmaxf(v, logit - pen);
        }
        v = fmaxf(v, __shfl_xor(v, 16));
        v = fmaxf(v, __shfl_xor(v, 32));
        if (lane < 16) pm[wid][ni * 16 + lane] = v;
    }
    __syncthreads();
    if (t < 64) {
        float m = fmaxf(fmaxf(pm[0][t], pm[1][t]), fmaxf(pm[2][t], pm[3][t]));
        pmax[((size_t)b * 8 + blockIdx.x) * 64 + t] = m;
    }
}

__global__ void k_relmax_red(const float* __restrict__ pmax, float* __restrict__ t2rel) {
    int b = blockIdx.x, r = threadIdx.x;
    if (r >= R_) return;
    float m = -3.0e38f;
    for (int ch = 0; ch < 8; ++ch) m = fmaxf(m, pmax[((size_t)b * 8 + ch) * 64 + r]);
    t2rel[b * R_ + r] = m;
}

// ---------------- driver ----------------
extern "C" void kernel_launch(void* const* d_in, const int* in_sizes, int n_in,
                              void* d_out, int out_size, void* d_ws, size_t ws_size,
                              hipStream_t stream) {
    const float* encoder_o = (const float*)d_in[0];
    const float* h0 = (const float*)d_in[1];
    const float* c0 = (const float*)d_in[2];
    const float* sos_emb = (const float*)d_in[3];
    const float* rel_emb = (const float*)d_in[4];
    const float* W_ih = (const float*)d_in[5];
    const float* W_hh = (const float*)d_in[6];
    const float* b_ih = (const float*)d_in[7];
    const float* b_hh = (const float*)d_in[8];
    const float* W_attn = (const float*)d_in[9];
    const float* b_attn = (const float*)d_in[10];
    const float* conv_rel_w = (const float*)d_in[11];
    const float* conv_rel_b = (const float*)d_in[12];
    const float* conv_ent_w = (const float*)d_in[13];
    const float* conv_ent_b = (const float*)d_in[14];
    const float* W_rel = (const float*)d_in[15];
    const float* b_rel = (const float*)d_in[16];
    const float* w_e1 = (const float*)d_in[17];
    const float* b_e1 = (const float*)d_in[18];
    const float* w_e2 = (const float*)d_in[19];
    const float* b_e2 = (const float*)d_in[20];
    const int* T = (const int*)d_in[21];
    const int* R_in = (const int*)d_in[22];
    const int* S_K1 = (const int*)d_in[23];
    const int* S_K2 = (const int*)d_in[24];

    float* out = (float*)d_out;
    float* t1e1 = out;
    float* t1e2 = out + 32768;
    float* t2rel = out + 65536;
    float* t3e1 = out + 68736;
    float* t3e2 = out + 101504;

    float* ws = (float*)d_ws;
    size_t off = 0;
    float* encA = ws + off; off += (size_t)B_ * L_ * E_;
    float* encB = ws + off; off += (size_t)B_ * L_ * E_;
    float* gates = ws + off; off += (size_t)B_ * 1024;
    float* hbuf = ws + off; off += B_ * H_;
    float* cbuf = ws + off; off += B_ * H_;
    float* inp  = ws + off; off += B_ * E_;
    float* aout = ws + off; off += B_ * E_;
    float* fullv = ws + off; off += B_ * E_;
    float* cr0  = ws + off; off += B_ * E_;
    float* cr2  = ws + off; off += B_ * E_;
    float* mixp = ws + off; off += (size_t)B_ * 4 * E_;
    float* stats = ws + off; off += B_ * 4 * 2;
    float* pmax = ws + off; off += B_ * 8 * 64;
    unsigned short* bpE = (unsigned short*)(ws + off); off += 16 * 24 * 64 * 8 / 2;
    unsigned short* bpR = (unsigned short*)(ws + off); off += 16 * 24 * 64 * 8 / 2;
    unsigned short* wpR = (unsigned short*)(ws + off); off += 4 * 8 * 64 * 8 / 2;

    dim3 convGrid(4, 8, B_);
    dim3 attnGrid(4, B_);
    dim3 rmGrid(8, B_);

    k_packB<<<96, 256, 0, stream>>>(conv_ent_w, bpE);
    k_packB<<<96, 256, 0, stream>>>(conv_rel_w, bpR);
    k_packW<<<8, 256, 0, stream>>>(W_rel, wpR);

    // ---- step 1: sos -> entity heads ----
    k_prep1<<<B_, 256, 0, stream>>>(sos_emb, inp);
    k_lstm_gemm<<<16, 256, 0, stream>>>(inp, h0, W_ih, W_hh, gates);
    k_lstm_fin<<<B_, 256, 0, stream>>>(gates, b_ih, b_hh, c0, hbuf, cbuf);
    k_attn_part<<<attnGrid, 256, 0, stream>>>(hbuf, encoder_o, mixp, stats);
    k_attn_comb<<<B_, 256, 0, stream>>>(mixp, stats, hbuf, W_attn, b_attn, aout);
    k_ocontrib<<<B_, 256, 0, stream>>>(aout, conv_ent_w, fullv, cr0, cr2);
    k_conv_mfma<<<convGrid, 256, 0, stream>>>(encoder_o, bpE, conv_ent_b, fullv, cr0, cr2, encA);
    k_heads<<<B_ * L_ / 4, 256, 0, stream>>>(encA, w_e1, b_e1, w_e2, b_e2, t1e1, t1e2);

    // ---- step 2: gathered entity spans -> relation logits ----
    k_prep2<<<B_, 256, 0, stream>>>(encA, S_K1, S_K2, inp);
    k_lstm_gemm<<<16, 256, 0, stream>>>(inp, hbuf, W_ih, W_hh, gates);
    k_lstm_fin<<<B_, 256, 0, stream>>>(gates, b_ih, b_hh, cbuf, hbuf, cbuf);
    k_attn_part<<<attnGrid, 256, 0, stream>>>(hbuf, encA, mixp, stats);
    k_attn_comb<<<B_, 256, 0, stream>>>(mixp, stats, hbuf, W_attn, b_attn, aout);
    k_ocontrib<<<B_, 256, 0, stream>>>(aout, conv_rel_w, fullv, cr0, cr2);
    k_conv_mfma<<<convGrid, 256, 0, stream>>>(encA, bpR, conv_rel_b, fullv, cr0, cr2, encB);
    k_relmax_mfma<<<rmGrid, 256, 0, stream>>>(encB, wpR, b_rel, T, pmax);
    k_relmax_red<<<B_, 64, 0, stream>>>(pmax, t2rel);

    // ---- step 3: relation embedding -> entity heads ----
    k_prep3<<<B_, 256, 0, stream>>>(rel_emb, R_in, inp);
    k_lstm_gemm<<<16, 256, 0, stream>>>(inp, hbuf, W_ih, W_hh, gates);
    k_lstm_fin<<<B_, 256, 0, stream>>>(gates, b_ih, b_hh, cbuf, hbuf, cbuf);
    k_attn_part<<<attnGrid, 256, 0, stream>>>(hbuf, encB, mixp, stats);
    k_attn_comb<<<B_, 256, 0, stream>>>(mixp, stats, hbuf, W_attn, b_attn, aout);
    k_ocontrib<<<B_, 256, 0, stream>>>(aout, conv_ent_w, fullv, cr0, cr2);
    k_conv_mfma<<<convGrid, 256, 0, stream>>>(encB, bpE, conv_ent_b, fullv, cr0, cr2, encA);
    k_heads<<<B_ * L_ / 4, 256, 0, stream>>>(encA, w_e1, b_e1, w_e2, b_e2, t3e1, t3e2);
}

// Round 3
// 369.423 us; speedup vs baseline: 6.5050x; 1.2151x over previous
//
#include <hip/hip_runtime.h>
#include <math.h>

#define B_ 64
#define L_ 512
#define E_ 256
#define H_ 256
#define R_ 50
#define NEG_ 1.0e10f

typedef __bf16 bf16x8 __attribute__((ext_vector_type(8)));
typedef float f32x4 __attribute__((ext_vector_type(4)));

__device__ __forceinline__ float sigmoidf_(float x) { return 1.0f / (1.0f + expf(-x)); }
__device__ __forceinline__ float geluf_(float x) { return 0.5f * x * (1.0f + erff(x * 0.7071067811865476f)); }
__device__ __forceinline__ unsigned short f2bf(float x) {
    unsigned u = __float_as_uint(x);
    return (unsigned short)((u + 0x7fffu + ((u >> 16) & 1u)) >> 16);
}
__device__ __forceinline__ float bf2f(unsigned u) { return __uint_as_float(u << 16); }

// ---------------- one-time converts / packs ----------------
__global__ void k_tobf16(const float* __restrict__ in, unsigned short* __restrict__ out) {
    size_t idx = (size_t)blockIdx.x * 256 + threadIdx.x;
    float4 v = *(const float4*)&in[idx * 4];
    unsigned short s[4] = {f2bf(v.x), f2bf(v.y), f2bf(v.z), f2bf(v.w)};
    uint2 p;
    p.x = (unsigned)s[0] | ((unsigned)s[1] << 16);
    p.y = (unsigned)s[2] | ((unsigned)s[3] << 16);
    *(uint2*)&out[idx * 4] = p;
}

// pack conv weights (c<256) into MFMA B-frag order: bp[of 16][kc 24][lane 64][8]
__global__ void k_packB(const float* __restrict__ w, unsigned short* __restrict__ bp) {
    int idx = blockIdx.x * 256 + threadIdx.x;
    if (idx >= 16 * 24 * 64) return;
    int l = idx & 63, kc = (idx >> 6) % 24, of = idx / (24 * 64);
    int o = of * 16 + (l & 15);
    int k = kc >> 3;
    int cb = ((kc & 7) << 5) + ((l >> 4) << 3);
    unsigned short v[8];
#pragma unroll
    for (int j = 0; j < 8; ++j) v[j] = f2bf(w[(size_t)o * 1536 + (size_t)(cb + j) * 3 + k]);
    unsigned int* dst = (unsigned int*)&bp[(size_t)idx * 8];
#pragma unroll
    for (int j = 0; j < 4; ++j) dst[j] = (unsigned int)v[2 * j] | ((unsigned int)v[2 * j + 1] << 16);
}

// pack W_rel (50x256 -> pad 64) : wp[of 4][kc 8][lane 64][8]
__global__ void k_packW(const float* __restrict__ W_rel, unsigned short* __restrict__ wp) {
    int idx = blockIdx.x * 256 + threadIdx.x;
    if (idx >= 4 * 8 * 64) return;
    int l = idx & 63, kc = (idx >> 6) & 7, of = idx / (8 * 64);
    int r = of * 16 + (l & 15);
    int k = kc * 32 + ((l >> 4) << 3);
    unsigned short v[8];
#pragma unroll
    for (int j = 0; j < 8; ++j) v[j] = (r < R_) ? f2bf(W_rel[(size_t)r * E_ + k + j]) : 0;
    unsigned int* dst = (unsigned int*)&wp[(size_t)idx * 8];
#pragma unroll
    for (int j = 0; j < 4; ++j) dst[j] = (unsigned int)v[2 * j] | ((unsigned int)v[2 * j + 1] << 16);
}

// pack ocontrib weights: wpk[0][c][o]=w0, wpk[1][c][o]=w0+w1+w2, wpk[2][c][o]=w2 (c = 256..511)
__global__ void k_packC(const float* __restrict__ w, float* __restrict__ wpk) {
    int idx = blockIdx.x * 256 + threadIdx.x; // 65536
    int o = idx >> 8, c = idx & 255;
    const float* p = &w[(size_t)o * 1536 + 768 + c * 3];
    float w0 = p[0], w1 = p[1], w2 = p[2];
    wpk[c * 256 + o] = w0;
    wpk[65536 + c * 256 + o] = w0 + w1 + w2;
    wpk[131072 + c * 256 + o] = w2;
}

// transpose W_attn (256 x 512) -> WT[k][o]
__global__ void k_packWT(const float* __restrict__ W_attn, float* __restrict__ WT) {
    int idx = blockIdx.x * 256 + threadIdx.x; // 131072
    int o = idx >> 9, k = idx & 511;
    WT[k * 256 + o] = W_attn[idx];
}

// ---------------- LSTM gemm halves with fused input prep ----------------
// grid (16, 2): y=0 -> X(input) @ W_ih^T, y=1 -> h @ W_hh^T ; gates[half][64][1024]
template <int MODE>
__global__ __launch_bounds__(256) void k_lstm_gemm(
    const float* __restrict__ xsrc_f, const unsigned short* __restrict__ encg,
    const int* __restrict__ i1, const int* __restrict__ i2, const int* __restrict__ rin,
    const float* __restrict__ hprev,
    const float* __restrict__ W_ih, const float* __restrict__ W_hh,
    float* __restrict__ gates) {
    const int g0 = blockIdx.x * 64;
    const int half = blockIdx.y;
    const int t = threadIdx.x, tx = t & 15, ty = t >> 4;
    __shared__ float Xs[64][68];
    __shared__ float Wt[64][68];
    const float* Wsrc = half ? W_hh : W_ih;
    float acc[4][4] = {{0.f}};
    for (int kb = 0; kb < 256; kb += 64) {
        __syncthreads();
#pragma unroll
        for (int i = 0; i < 4; ++i) {
            int idx = i * 256 + t;
            int row = idx >> 4, kk = (idx & 15) << 2;
            float4 xv;
            if (half) {
                xv = *(const float4*)&hprev[row * 256 + kb + kk];
            } else if (MODE == 0) {
                xv = *(const float4*)&xsrc_f[kb + kk];
            } else if (MODE == 2) {
                xv = *(const float4*)&xsrc_f[(size_t)rin[row] * 256 + kb + kk];
            } else {
                const unsigned short* p1 = &encg[((size_t)row * L_ + i1[row]) * E_ + kb + kk];
                const unsigned short* p2 = &encg[((size_t)row * L_ + i2[row]) * E_ + kb + kk];
                uint2 a = *(const uint2*)p1, b2 = *(const uint2*)p2;
                xv.x = bf2f(a.x & 0xffffu) + bf2f(b2.x & 0xffffu);
                xv.y = bf2f(a.x >> 16) + bf2f(b2.x >> 16);
                xv.z = bf2f(a.y & 0xffffu) + bf2f(b2.y & 0xffffu);
                xv.w = bf2f(a.y >> 16) + bf2f(b2.y >> 16);
            }
            *(float4*)&Xs[row][kk] = xv;
            *(float4*)&Wt[row][kk] = *(const float4*)&Wsrc[(size_t)(g0 + row) * 256 + kb + kk];
        }
        __syncthreads();
#pragma unroll
        for (int kk = 0; kk < 64; kk += 4) {
            float4 xv[4], wv[4];
#pragma unroll
            for (int i = 0; i < 4; ++i) xv[i] = *(const float4*)&Xs[ty * 4 + i][kk];
#pragma unroll
            for (int j = 0; j < 4; ++j) wv[j] = *(const float4*)&Wt[tx * 4 + j][kk];
#pragma unroll
            for (int i = 0; i < 4; ++i)
#pragma unroll
                for (int j = 0; j < 4; ++j)
                    acc[i][j] += xv[i].x * wv[j].x + xv[i].y * wv[j].y + xv[i].z * wv[j].z + xv[i].w * wv[j].w;
        }
    }
#pragma unroll
    for (int i = 0; i < 4; ++i)
#pragma unroll
        for (int j = 0; j < 4; ++j)
            gates[(size_t)half * 65536 + (size_t)(ty * 4 + i) * 1024 + g0 + tx * 4 + j] = acc[i][j];
}

// ---------------- attention partial with fused LSTM finish ----------------
__global__ __launch_bounds__(256) void k_attn_part(
    const float* __restrict__ gates, const float* __restrict__ b_ih, const float* __restrict__ b_hh,
    const float* __restrict__ c_in, float* __restrict__ c_out, float* __restrict__ h_out,
    const unsigned short* __restrict__ encbf,
    float* __restrict__ mixp, float* __restrict__ stats) {
    int b = blockIdx.y, ch = blockIdx.x, t = threadIdx.x;
    __shared__ float hs[E_];
    __shared__ float sc[128];
    __shared__ float red[4], red2[4];
    {
        size_t ba = (size_t)b * 1024;
        float gi = gates[ba + t] + gates[65536 + ba + t] + b_ih[t] + b_hh[t];
        float gf = gates[ba + 256 + t] + gates[65536 + ba + 256 + t] + b_ih[256 + t] + b_hh[256 + t];
        float gg = gates[ba + 512 + t] + gates[65536 + ba + 512 + t] + b_ih[512 + t] + b_hh[512 + t];
        float go = gates[ba + 768 + t] + gates[65536 + ba + 768 + t] + b_ih[768 + t] + b_hh[768 + t];
        float c = sigmoidf_(gf) * c_in[b * H_ + t] + sigmoidf_(gi) * tanhf(gg);
        float hv = sigmoidf_(go) * tanhf(c);
        hs[t] = hv;
        if (ch == 0) { h_out[b * H_ + t] = hv; c_out[b * H_ + t] = c; }
    }
    __syncthreads();
    if (t < 128) {
        const uint4* row = (const uint4*)&encbf[((size_t)b * L_ + ch * 128 + t) * E_];
        float acc = 0.f;
#pragma unroll 4
        for (int k = 0; k < 32; ++k) {
            uint4 q = row[k];
            acc += bf2f(q.x & 0xffffu) * hs[k * 8 + 0] + bf2f(q.x >> 16) * hs[k * 8 + 1]
                 + bf2f(q.y & 0xffffu) * hs[k * 8 + 2] + bf2f(q.y >> 16) * hs[k * 8 + 3]
                 + bf2f(q.z & 0xffffu) * hs[k * 8 + 4] + bf2f(q.z >> 16) * hs[k * 8 + 5]
                 + bf2f(q.w & 0xffffu) * hs[k * 8 + 6] + bf2f(q.w >> 16) * hs[k * 8 + 7];
        }
        sc[t] = acc;
    }
    __syncthreads();
    float v = (t < 128) ? sc[t] : -3.0e38f;
#pragma unroll
    for (int off = 32; off; off >>= 1) v = fmaxf(v, __shfl_xor(v, off));
    if ((t & 63) == 0) red[t >> 6] = v;
    __syncthreads();
    float m = fmaxf(fmaxf(red[0], red[1]), fmaxf(red[2], red[3]));
    float ev = (t < 128) ? expf(sc[t] - m) : 0.f;
    float sv = ev;
#pragma unroll
    for (int off = 32; off; off >>= 1) sv += __shfl_xor(sv, off);
    if ((t & 63) == 0) red2[t >> 6] = sv;
    if (t < 128) sc[t] = ev;
    __syncthreads();
    float s = red2[0] + red2[1] + red2[2] + red2[3];
    float acc = 0.f;
    const unsigned short* base = &encbf[((size_t)b * L_ + ch * 128) * E_ + t];
#pragma unroll 8
    for (int l = 0; l < 128; ++l) acc += sc[l] * bf2f(base[(size_t)l * E_]);
    mixp[((size_t)b * 4 + ch) * E_ + t] = acc;
    if (t == 0) {
        stats[((size_t)b * 4 + ch) * 2] = m;
        stats[((size_t)b * 4 + ch) * 2 + 1] = s;
    }
}

// ---------------- combine + attn-out GEMV + ocontrib (fullv/cr0/cr2) ----------------
__global__ __launch_bounds__(256) void k_post(
    const float* __restrict__ mixp, const float* __restrict__ stats,
    const float* __restrict__ h, const float* __restrict__ WT_attn,
    const float* __restrict__ b_attn, const float* __restrict__ wpk,
    float* __restrict__ fullv, float* __restrict__ cr0, float* __restrict__ cr2) {
    int b = blockIdx.x, t = threadIdx.x;
    __shared__ float cat[2 * E_];
    __shared__ float os[E_];
    float m0 = stats[(b * 4 + 0) * 2], m1 = stats[(b * 4 + 1) * 2];
    float m2 = stats[(b * 4 + 2) * 2], m3 = stats[(b * 4 + 3) * 2];
    float M = fmaxf(fmaxf(m0, m1), fmaxf(m2, m3));
    float w0 = expf(m0 - M), w1 = expf(m1 - M), w2 = expf(m2 - M), w3 = expf(m3 - M);
    float denom = stats[(b * 4 + 0) * 2 + 1] * w0 + stats[(b * 4 + 1) * 2 + 1] * w1 +
                  stats[(b * 4 + 2) * 2 + 1] * w2 + stats[(b * 4 + 3) * 2 + 1] * w3;
    float mixv = (mixp[((size_t)b * 4 + 0) * E_ + t] * w0 + mixp[((size_t)b * 4 + 1) * E_ + t] * w1 +
                  mixp[((size_t)b * 4 + 2) * E_ + t] * w2 + mixp[((size_t)b * 4 + 3) * E_ + t] * w3) / denom;
    cat[t] = mixv;
    cat[E_ + t] = h[b * E_ + t];
    __syncthreads();
    float acc = b_attn[t];
#pragma unroll 8
    for (int k = 0; k < 512; ++k) acc += cat[k] * WT_attn[k * 256 + t];
    float ao = tanhf(acc);
    os[t] = ao;
    __syncthreads();
    float f = 0.f, a0 = 0.f, a2 = 0.f;
#pragma unroll 4
    for (int c = 0; c < 256; ++c) {
        float vv = os[c];
        a0 += vv * wpk[c * 256 + t];
        f  += vv * wpk[65536 + c * 256 + t];
        a2 += vv * wpk[131072 + c * 256 + t];
    }
    fullv[b * E_ + t] = f;
    cr0[b * E_ + t] = a0;
    cr2[b * E_ + t] = a2;
}

// ---------------- conv as bf16 MFMA GEMM, 64l x 256o per block, fused heads ----------------
template <bool FUSE_HEADS, bool WRITE_OUT>
__global__ __launch_bounds__(256) void k_conv_mfma(
    const unsigned short* __restrict__ encbf, const unsigned short* __restrict__ bp,
    const float* __restrict__ bias, const float* __restrict__ fullv,
    const float* __restrict__ cr0, const float* __restrict__ cr2,
    unsigned short* __restrict__ enc_out,
    const float* __restrict__ w_e1, const float* __restrict__ b_e1,
    const float* __restrict__ w_e2, const float* __restrict__ b_e2,
    float* __restrict__ o1, float* __restrict__ o2) {
    const int b = blockIdx.y, l0 = blockIdx.x * 64;
    const int t = threadIdx.x, lane = t & 63, wid = t >> 6;
    __shared__ unsigned short As[66 * 256];   // swizzled A in; reused as out tile
    __shared__ float hsum[2][4][64];

    // stage A: rows 0..65 <-> l = l0-1+row, 16B units
    for (int u = t; u < 66 * 32; u += 256) {
        int row = u >> 5, cu = u & 31;
        int l = l0 - 1 + row;
        uint4 v = {0u, 0u, 0u, 0u};
        if (l >= 0 && l < L_) v = *(const uint4*)&encbf[((size_t)b * L_ + l) * E_ + cu * 8];
        *(uint4*)&As[row * 256 + ((cu ^ (row & 7)) << 3)] = v;
    }
    __syncthreads();

    const int wo4 = wid * 4;                 // this wave's o-frag base (4 frags = 64 o)
    f32x4 zero = {0.f, 0.f, 0.f, 0.f};
    f32x4 acc[4][4];
#pragma unroll
    for (int i = 0; i < 4; ++i)
#pragma unroll
        for (int j = 0; j < 4; ++j) acc[i][j] = zero;
    const int arow = lane & 15, agrp = lane >> 4;

#pragma unroll 2
    for (int kc = 0; kc < 24; ++kc) {
        const int k = kc >> 3;
        const int g = ((kc & 7) << 2) + agrp;
        bf16x8 a[4], bv[4];
#pragma unroll
        for (int mi = 0; mi < 4; ++mi) {
            int r = mi * 16 + arow + k;
            a[mi] = *(const bf16x8*)&As[r * 256 + ((g ^ (r & 7)) << 3)];
        }
#pragma unroll
        for (int ni = 0; ni < 4; ++ni)
            bv[ni] = *(const bf16x8*)&bp[(((size_t)(wo4 + ni) * 24 + kc) * 64 + lane) * 8];
#pragma unroll
        for (int mi = 0; mi < 4; ++mi)
#pragma unroll
            for (int ni = 0; ni < 4; ++ni)
                acc[mi][ni] = __builtin_amdgcn_mfma_f32_16x16x32_bf16(a[mi], bv[ni], acc[mi][ni], 0, 0, 0);
    }

    // per-lane epilogue constants
    float biasv[4], c0v[4], c2v[4], we1[4], we2[4];
#pragma unroll
    for (int ni = 0; ni < 4; ++ni) {
        int o = (wo4 + ni) * 16 + (lane & 15);
        biasv[ni] = bias[o] + fullv[b * E_ + o];
        c0v[ni] = cr0[b * E_ + o];
        c2v[ni] = cr2[b * E_ + o];
        if (FUSE_HEADS) { we1[ni] = w_e1[o]; we2[ni] = w_e2[o]; }
    }
    __syncthreads();   // done reading As; reuse as output tile

#pragma unroll
    for (int mi = 0; mi < 4; ++mi) {
#pragma unroll
        for (int r = 0; r < 4; ++r) {
            int lloc = mi * 16 + agrp * 4 + r;
            int lrow = l0 + lloc;
            float p1 = 0.f, p2 = 0.f;
#pragma unroll
            for (int ni = 0; ni < 4; ++ni) {
                float vv = acc[mi][ni][r] + biasv[ni];
                if (lrow == 0) vv -= c0v[ni];
                if (lrow == L_ - 1) vv -= c2v[ni];
                if (WRITE_OUT) As[lloc * 256 + (wo4 + ni) * 16 + (lane & 15)] = f2bf(vv);
                if (FUSE_HEADS) {
                    float gv = geluf_(vv);
                    p1 += gv * we1[ni];
                    p2 += gv * we2[ni];
                }
            }
            if (FUSE_HEADS) {
#pragma unroll
                for (int off = 1; off < 16; off <<= 1) {
                    p1 += __shfl_xor(p1, off);
                    p2 += __shfl_xor(p2, off);
                }
                if ((lane & 15) == 0) {
                    hsum[0][wid][lloc] = p1;
                    hsum[1][wid][lloc] = p2;
                }
            }
        }
    }
    __syncthreads();
    if (WRITE_OUT) {
        for (int u = t; u < 64 * 32; u += 256) {
            int row = u >> 5, cu = u & 31;
            *(uint4*)&enc_out[((size_t)b * L_ + l0 + row) * E_ + cu * 8] = *(const uint4*)&As[row * 256 + cu * 8];
        }
    }
    if (FUSE_HEADS && t < 128) {
        int hh = t >> 6, row = t & 63;
        float s = hsum[hh][0][row] + hsum[hh][1][row] + hsum[hh][2][row] + hsum[hh][3][row];
        float* dst = hh ? o2 : o1;
        const float* bb = hh ? b_e2 : b_e1;
        dst[(size_t)b * L_ + l0 + row] = s + bb[0];
    }
}

// ---------------- relation head: MFMA gelu(enc) @ W_rel^T, masked max ----------------
__global__ __launch_bounds__(256) void k_relmax_mfma(
    const unsigned short* __restrict__ encbf, const unsigned short* __restrict__ wp,
    const float* __restrict__ b_rel, const int* __restrict__ T,
    float* __restrict__ pmax) {
    const int b = blockIdx.y, l0 = blockIdx.x * 64;
    const int t = threadIdx.x, lane = t & 63, wid = t >> 6;
    __shared__ unsigned short As[64 * 256];
    __shared__ int Tm[64];
    __shared__ float pm[4][64];

    if (t < 64) Tm[t] = T[b * L_ + l0 + t];
    for (int u = t; u < 64 * 32; u += 256) {
        int row = u >> 5, cu = u & 31;
        uint4 q = *(const uint4*)&encbf[((size_t)b * L_ + l0 + row) * E_ + cu * 8];
        unsigned short s[8];
        unsigned qa[4] = {q.x, q.y, q.z, q.w};
#pragma unroll
        for (int j = 0; j < 4; ++j) {
            s[2 * j] = f2bf(geluf_(bf2f(qa[j] & 0xffffu)));
            s[2 * j + 1] = f2bf(geluf_(bf2f(qa[j] >> 16)));
        }
        uint4 p;
        p.x = (unsigned)s[0] | ((unsigned)s[1] << 16);
        p.y = (unsigned)s[2] | ((unsigned)s[3] << 16);
        p.z = (unsigned)s[4] | ((unsigned)s[5] << 16);
        p.w = (unsigned)s[6] | ((unsigned)s[7] << 16);
        *(uint4*)&As[row * 256 + ((cu ^ (row & 7)) << 3)] = p;
    }
    __syncthreads();

    f32x4 zero = {0.f, 0.f, 0.f, 0.f};
    f32x4 acc[4] = {zero, zero, zero, zero};
    const int arow = wid * 16 + (lane & 15);
    const int agrp = lane >> 4;
#pragma unroll 2
    for (int kc = 0; kc < 8; ++kc) {
        int g = (kc << 2) + agrp;
        bf16x8 a0 = *(const bf16x8*)&As[arow * 256 + ((g ^ (arow & 7)) << 3)];
#pragma unroll
        for (int ni = 0; ni < 4; ++ni) {
            bf16x8 bv = *(const bf16x8*)&wp[(((size_t)ni * 8 + kc) * 64 + lane) * 8];
            acc[ni] = __builtin_amdgcn_mfma_f32_16x16x32_bf16(a0, bv, acc[ni], 0, 0, 0);
        }
    }

    const int lloc_base = wid * 16 + ((lane >> 4) << 2);
#pragma unroll
    for (int ni = 0; ni < 4; ++ni) {
        int r = ni * 16 + (lane & 15);
        float brel = (r < R_) ? b_rel[r] : 0.f;
        float v = -3.0e38f;
#pragma unroll
        for (int rg = 0; rg < 4; ++rg) {
            float logit = acc[ni][rg] + brel;
            float pen = (Tm[lloc_base + rg] > 0) ? 0.f : NEG_;
            v = fmaxf(v, logit - pen);
        }
        v = fmaxf(v, __shfl_xor(v, 16));
        v = fmaxf(v, __shfl_xor(v, 32));
        if (lane < 16) pm[wid][ni * 16 + lane] = v;
    }
    __syncthreads();
    if (t < 64) {
        float m = fmaxf(fmaxf(pm[0][t], pm[1][t]), fmaxf(pm[2][t], pm[3][t]));
        pmax[((size_t)b * 8 + blockIdx.x) * 64 + t] = m;
    }
}

__global__ void k_relmax_red(const float* __restrict__ pmax, float* __restrict__ t2rel) {
    int b = blockIdx.x, r = threadIdx.x;
    if (r >= R_) return;
    float m = -3.0e38f;
    for (int ch = 0; ch < 8; ++ch) m = fmaxf(m, pmax[((size_t)b * 8 + ch) * 64 + r]);
    t2rel[b * R_ + r] = m;
}

// ---------------- driver ----------------
extern "C" void kernel_launch(void* const* d_in, const int* in_sizes, int n_in,
                              void* d_out, int out_size, void* d_ws, size_t ws_size,
                              hipStream_t stream) {
    const float* encoder_o = (const float*)d_in[0];
    const float* h0 = (const float*)d_in[1];
    const float* c0 = (const float*)d_in[2];
    const float* sos_emb = (const float*)d_in[3];
    const float* rel_emb = (const float*)d_in[4];
    const float* W_ih = (const float*)d_in[5];
    const float* W_hh = (const float*)d_in[6];
    const float* b_ih = (const float*)d_in[7];
    const float* b_hh = (const float*)d_in[8];
    const float* W_attn = (const float*)d_in[9];
    const float* b_attn = (const float*)d_in[10];
    const float* conv_rel_w = (const float*)d_in[11];
    const float* conv_rel_b = (const float*)d_in[12];
    const float* conv_ent_w = (const float*)d_in[13];
    const float* conv_ent_b = (const float*)d_in[14];
    const float* W_rel = (const float*)d_in[15];
    const float* b_rel = (const float*)d_in[16];
    const float* w_e1 = (const float*)d_in[17];
    const float* b_e1 = (const float*)d_in[18];
    const float* w_e2 = (const float*)d_in[19];
    const float* b_e2 = (const float*)d_in[20];
    const int* T = (const int*)d_in[21];
    const int* R_in = (const int*)d_in[22];
    const int* S_K1 = (const int*)d_in[23];
    const int* S_K2 = (const int*)d_in[24];

    float* out = (float*)d_out;
    float* t1e1 = out;
    float* t1e2 = out + 32768;
    float* t2rel = out + 65536;
    float* t3e1 = out + 68736;
    float* t3e2 = out + 101504;

    float* ws = (float*)d_ws;
    size_t off = 0;
    unsigned short* encBF0 = (unsigned short*)(ws + off); off += (size_t)B_ * L_ * E_ / 2;
    unsigned short* encA = (unsigned short*)(ws + off); off += (size_t)B_ * L_ * E_ / 2;
    unsigned short* encB = (unsigned short*)(ws + off); off += (size_t)B_ * L_ * E_ / 2;
    float* gates = ws + off; off += 2 * 65536;
    float* hbuf = ws + off; off += B_ * H_;
    float* cb1 = ws + off; off += B_ * H_;
    float* cb2 = ws + off; off += B_ * H_;
    float* cb3 = ws + off; off += B_ * H_;
    float* mixp = ws + off; off += (size_t)B_ * 4 * E_;
    float* stats = ws + off; off += B_ * 4 * 2;
    float* fullv = ws + off; off += B_ * E_;
    float* cr0 = ws + off; off += B_ * E_;
    float* cr2 = ws + off; off += B_ * E_;
    float* pmax = ws + off; off += B_ * 8 * 64;
    float* wpkE = ws + off; off += 3 * 65536;
    float* wpkR = ws + off; off += 3 * 65536;
    float* WTat = ws + off; off += 131072;
    unsigned short* bpE = (unsigned short*)(ws + off); off += 16 * 24 * 64 * 8 / 2;
    unsigned short* bpR = (unsigned short*)(ws + off); off += 16 * 24 * 64 * 8 / 2;
    unsigned short* wpR = (unsigned short*)(ws + off); off += 4 * 8 * 64 * 8 / 2;

    dim3 convGrid(8, B_);
    dim3 attnGrid(4, B_);
    dim3 rmGrid(8, B_);
    dim3 lstmGrid(16, 2);

    // one-time packs
    k_tobf16<<<(B_ * L_ * E_) / 1024, 256, 0, stream>>>(encoder_o, encBF0);
    k_packB<<<96, 256, 0, stream>>>(conv_ent_w, bpE);
    k_packB<<<96, 256, 0, stream>>>(conv_rel_w, bpR);
    k_packW<<<8, 256, 0, stream>>>(W_rel, wpR);
    k_packC<<<256, 256, 0, stream>>>(conv_ent_w, wpkE);
    k_packC<<<256, 256, 0, stream>>>(conv_rel_w, wpkR);
    k_packWT<<<512, 256, 0, stream>>>(W_attn, WTat);

    // ---- step 1 ----
    k_lstm_gemm<0><<<lstmGrid, 256, 0, stream>>>(sos_emb, nullptr, nullptr, nullptr, nullptr,
                                                 h0, W_ih, W_hh, gates);
    k_attn_part<<<attnGrid, 256, 0, stream>>>(gates, b_ih, b_hh, c0, cb1, hbuf, encBF0, mixp, stats);
    k_post<<<B_, 256, 0, stream>>>(mixp, stats, hbuf, WTat, b_attn, wpkE, fullv, cr0, cr2);
    k_conv_mfma<true, true><<<convGrid, 256, 0, stream>>>(encBF0, bpE, conv_ent_b, fullv, cr0, cr2,
                                                          encA, w_e1, b_e1, w_e2, b_e2, t1e1, t1e2);

    // ---- step 2 ----
    k_lstm_gemm<1><<<lstmGrid, 256, 0, stream>>>(nullptr, encA, S_K1, S_K2, nullptr,
                                                 hbuf, W_ih, W_hh, gates);
    k_attn_part<<<attnGrid, 256, 0, stream>>>(gates, b_ih, b_hh, cb1, cb2, hbuf, encA, mixp, stats);
    k_post<<<B_, 256, 0, stream>>>(mixp, stats, hbuf, WTat, b_attn, wpkR, fullv, cr0, cr2);
    k_conv_mfma<false, true><<<convGrid, 256, 0, stream>>>(encA, bpR, conv_rel_b, fullv, cr0, cr2,
                                                           encB, nullptr, nullptr, nullptr, nullptr,
                                                           nullptr, nullptr);
    k_relmax_mfma<<<rmGrid, 256, 0, stream>>>(encB, wpR, b_rel, T, pmax);
    k_relmax_red<<<B_, 64, 0, stream>>>(pmax, t2rel);

    // ---- step 3 ----
    k_lstm_gemm<2><<<lstmGrid, 256, 0, stream>>>(rel_emb, nullptr, nullptr, nullptr, R_in,
                                                 hbuf, W_ih, W_hh, gates);
    k_attn_part<<<attnGrid, 256, 0, stream>>>(gates, b_ih, b_hh, cb2, cb3, hbuf, encB, mixp, stats);
    k_post<<<B_, 256, 0, stream>>>(mixp, stats, hbuf, WTat, b_attn, wpkE, fullv, cr0, cr2);
    k_conv_mfma<true, false><<<convGrid, 256, 0, stream>>>(encB, bpE, conv_ent_b, fullv, cr0, cr2,
                                                           nullptr, w_e1, b_e1, w_e2, b_e2, t3e1, t3e2);
}

// Round 4
// 227.370 us; speedup vs baseline: 10.5691x; 1.6248x over previous
//
#include <hip/hip_runtime.h>
#include <math.h>

#define B_ 64
#define L_ 512
#define E_ 256
#define H_ 256
#define R_ 50
#define NEG_ 1.0e10f

typedef __bf16 bf16x8 __attribute__((ext_vector_type(8)));
typedef float f32x4 __attribute__((ext_vector_type(4)));

__device__ __forceinline__ float sigmoidf_(float x) { return 1.0f / (1.0f + expf(-x)); }
__device__ __forceinline__ float geluf_(float x) { return 0.5f * x * (1.0f + erff(x * 0.7071067811865476f)); }
__device__ __forceinline__ unsigned short f2bf(float x) {
    unsigned u = __float_as_uint(x);
    return (unsigned short)((u + 0x7fffu + ((u >> 16) & 1u)) >> 16);
}
__device__ __forceinline__ float bf2f(unsigned u) { return __uint_as_float(u << 16); }

// ---------------- one-time converts / packs ----------------
__global__ void k_tobf16(const float* __restrict__ in, unsigned short* __restrict__ out) {
    size_t idx = (size_t)blockIdx.x * 256 + threadIdx.x;
    float4 v = *(const float4*)&in[idx * 4];
    unsigned short s[4] = {f2bf(v.x), f2bf(v.y), f2bf(v.z), f2bf(v.w)};
    uint2 p;
    p.x = (unsigned)s[0] | ((unsigned)s[1] << 16);
    p.y = (unsigned)s[2] | ((unsigned)s[3] << 16);
    *(uint2*)&out[idx * 4] = p;
}

// pack conv weights (c<256) into MFMA B-frag order: bp[of 16][kc 24][lane 64][8]
__global__ void k_packB(const float* __restrict__ w, unsigned short* __restrict__ bp) {
    int idx = blockIdx.x * 256 + threadIdx.x;
    if (idx >= 16 * 24 * 64) return;
    int l = idx & 63, kc = (idx >> 6) % 24, of = idx / (24 * 64);
    int o = of * 16 + (l & 15);
    int k = kc >> 3;
    int cb = ((kc & 7) << 5) + ((l >> 4) << 3);
    unsigned short v[8];
#pragma unroll
    for (int j = 0; j < 8; ++j) v[j] = f2bf(w[(size_t)o * 1536 + (size_t)(cb + j) * 3 + k]);
    unsigned int* dst = (unsigned int*)&bp[(size_t)idx * 8];
#pragma unroll
    for (int j = 0; j < 4; ++j) dst[j] = (unsigned int)v[2 * j] | ((unsigned int)v[2 * j + 1] << 16);
}

// pack W_rel (50x256 -> pad 64) : wp[of 4][kc 8][lane 64][8]
__global__ void k_packW(const float* __restrict__ W_rel, unsigned short* __restrict__ wp) {
    int idx = blockIdx.x * 256 + threadIdx.x;
    if (idx >= 4 * 8 * 64) return;
    int l = idx & 63, kc = (idx >> 6) & 7, of = idx / (8 * 64);
    int r = of * 16 + (l & 15);
    int k = kc * 32 + ((l >> 4) << 3);
    unsigned short v[8];
#pragma unroll
    for (int j = 0; j < 8; ++j) v[j] = (r < R_) ? f2bf(W_rel[(size_t)r * E_ + k + j]) : 0;
    unsigned int* dst = (unsigned int*)&wp[(size_t)idx * 8];
#pragma unroll
    for (int j = 0; j < 4; ++j) dst[j] = (unsigned int)v[2 * j] | ((unsigned int)v[2 * j + 1] << 16);
}

// pack ocontrib weights: wpk[0][c][o]=w0, wpk[1][c][o]=w0+w1+w2, wpk[2][c][o]=w2 (c = 256..511)
__global__ void k_packC(const float* __restrict__ w, float* __restrict__ wpk) {
    int idx = blockIdx.x * 256 + threadIdx.x; // 65536
    int o = idx >> 8, c = idx & 255;
    const float* p = &w[(size_t)o * 1536 + 768 + c * 3];
    float w0 = p[0], w1 = p[1], w2 = p[2];
    wpk[c * 256 + o] = w0;
    wpk[65536 + c * 256 + o] = w0 + w1 + w2;
    wpk[131072 + c * 256 + o] = w2;
}

// transpose W_attn (256 x 512) -> WT[k][o]
__global__ void k_packWT(const float* __restrict__ W_attn, float* __restrict__ WT) {
    int idx = blockIdx.x * 256 + threadIdx.x; // 131072
    int o = idx >> 9, k = idx & 511;
    WT[k * 256 + o] = W_attn[idx];
}

// ---------------- LSTM gemm, split-K: grid (16, 2, 2) ----------------
// gates segment seg = half*2 + z, each [64][1024]
template <int MODE>
__global__ __launch_bounds__(256) void k_lstm_gemm(
    const float* __restrict__ xsrc_f, const unsigned short* __restrict__ encg,
    const int* __restrict__ i1, const int* __restrict__ i2, const int* __restrict__ rin,
    const float* __restrict__ hprev,
    const float* __restrict__ W_ih, const float* __restrict__ W_hh,
    float* __restrict__ gates) {
    const int g0 = blockIdx.x * 64;
    const int half = blockIdx.y, z = blockIdx.z;
    const int t = threadIdx.x, tx = t & 15, ty = t >> 4;
    __shared__ float Xs[64][68];
    __shared__ float Wt[64][68];
    const float* Wsrc = half ? W_hh : W_ih;
    float acc[4][4] = {{0.f}};
    for (int kb = z * 128; kb < z * 128 + 128; kb += 64) {
        __syncthreads();
#pragma unroll
        for (int i = 0; i < 4; ++i) {
            int idx = i * 256 + t;
            int row = idx >> 4, kk = (idx & 15) << 2;
            float4 xv;
            if (half) {
                xv = *(const float4*)&hprev[row * 256 + kb + kk];
            } else if (MODE == 0) {
                xv = *(const float4*)&xsrc_f[kb + kk];
            } else if (MODE == 2) {
                xv = *(const float4*)&xsrc_f[(size_t)rin[row] * 256 + kb + kk];
            } else {
                const unsigned short* p1 = &encg[((size_t)row * L_ + i1[row]) * E_ + kb + kk];
                const unsigned short* p2 = &encg[((size_t)row * L_ + i2[row]) * E_ + kb + kk];
                uint2 a = *(const uint2*)p1, b2 = *(const uint2*)p2;
                xv.x = bf2f(a.x & 0xffffu) + bf2f(b2.x & 0xffffu);
                xv.y = bf2f(a.x >> 16) + bf2f(b2.x >> 16);
                xv.z = bf2f(a.y & 0xffffu) + bf2f(b2.y & 0xffffu);
                xv.w = bf2f(a.y >> 16) + bf2f(b2.y >> 16);
            }
            *(float4*)&Xs[row][kk] = xv;
            *(float4*)&Wt[row][kk] = *(const float4*)&Wsrc[(size_t)(g0 + row) * 256 + kb + kk];
        }
        __syncthreads();
#pragma unroll
        for (int kk = 0; kk < 64; kk += 4) {
            float4 xv[4], wv[4];
#pragma unroll
            for (int i = 0; i < 4; ++i) xv[i] = *(const float4*)&Xs[ty * 4 + i][kk];
#pragma unroll
            for (int j = 0; j < 4; ++j) wv[j] = *(const float4*)&Wt[tx * 4 + j][kk];
#pragma unroll
            for (int i = 0; i < 4; ++i)
#pragma unroll
                for (int j = 0; j < 4; ++j)
                    acc[i][j] += xv[i].x * wv[j].x + xv[i].y * wv[j].y + xv[i].z * wv[j].z + xv[i].w * wv[j].w;
        }
    }
    const int seg = half * 2 + z;
#pragma unroll
    for (int i = 0; i < 4; ++i)
#pragma unroll
        for (int j = 0; j < 4; ++j)
            gates[(size_t)seg * 65536 + (size_t)(ty * 4 + i) * 1024 + g0 + tx * 4 + j] = acc[i][j];
}

// ---------------- attention partial (64-l chunks) with fused LSTM finish ----------------
__global__ __launch_bounds__(256) void k_attn_part(
    const float* __restrict__ gates, const float* __restrict__ b_ih, const float* __restrict__ b_hh,
    const float* __restrict__ c_in, float* __restrict__ c_out, float* __restrict__ h_out,
    const unsigned short* __restrict__ encbf,
    float* __restrict__ mixp, float* __restrict__ stats) {
    int b = blockIdx.y, ch = blockIdx.x, t = threadIdx.x;
    __shared__ float hs[E_];
    __shared__ float scp[64][4];
    __shared__ float sc[64];
    {
        size_t ba = (size_t)b * 1024;
        float g4[4];
#pragma unroll
        for (int g = 0; g < 4; ++g) {
            float acc = b_ih[g * 256 + t] + b_hh[g * 256 + t];
#pragma unroll
            for (int seg = 0; seg < 4; ++seg) acc += gates[(size_t)seg * 65536 + ba + g * 256 + t];
            g4[g] = acc;
        }
        float c = sigmoidf_(g4[1]) * c_in[b * H_ + t] + sigmoidf_(g4[0]) * tanhf(g4[2]);
        float hv = sigmoidf_(g4[3]) * tanhf(c);
        hs[t] = hv;
        if (ch == 0) { h_out[b * H_ + t] = hv; c_out[b * H_ + t] = c; }
    }
    __syncthreads();
    // scores: 64 rows x 4 e-slices
    {
        int row = t >> 2, es = t & 3;
        const uint4* p = (const uint4*)&encbf[((size_t)b * L_ + ch * 64 + row) * E_ + es * 64];
        float acc = 0.f;
#pragma unroll
        for (int k = 0; k < 8; ++k) {
            uint4 q = p[k];
            int e0 = es * 64 + k * 8;
            acc += bf2f(q.x & 0xffffu) * hs[e0] + bf2f(q.x >> 16) * hs[e0 + 1]
                 + bf2f(q.y & 0xffffu) * hs[e0 + 2] + bf2f(q.y >> 16) * hs[e0 + 3]
                 + bf2f(q.z & 0xffffu) * hs[e0 + 4] + bf2f(q.z >> 16) * hs[e0 + 5]
                 + bf2f(q.w & 0xffffu) * hs[e0 + 6] + bf2f(q.w >> 16) * hs[e0 + 7];
        }
        scp[row][es] = acc;
    }
    __syncthreads();
    if (t < 64) {
        float v = scp[t][0] + scp[t][1] + scp[t][2] + scp[t][3];
        float m = v;
#pragma unroll
        for (int off = 32; off; off >>= 1) m = fmaxf(m, __shfl_xor(m, off));
        float ev = expf(v - m);
        float s = ev;
#pragma unroll
        for (int off = 32; off; off >>= 1) s += __shfl_xor(s, off);
        sc[t] = ev;
        if (t == 0) {
            stats[((size_t)b * 8 + ch) * 2] = m;
            stats[((size_t)b * 8 + ch) * 2 + 1] = s;
        }
    }
    __syncthreads();
    // mix: thread owns e=t, 64 l's
    float acc = 0.f;
    const unsigned short* base = &encbf[((size_t)b * L_ + ch * 64) * E_ + t];
#pragma unroll 8
    for (int l = 0; l < 64; ++l) acc += sc[l] * bf2f((unsigned)base[(size_t)l * E_]);
    mixp[((size_t)b * 8 + ch) * E_ + t] = acc;
}

// ---------------- post1: combine + attn-out GEMV (split-K), aout = tanh(cat @ WT + b) ----------------
__global__ __launch_bounds__(256) void k_post1(
    const float* __restrict__ mixp, const float* __restrict__ stats,
    const float* __restrict__ h, const float* __restrict__ WT_attn,
    const float* __restrict__ b_attn, float* __restrict__ aout) {
    int b = blockIdx.x, oc = blockIdx.y, t = threadIdx.x;
    __shared__ float cat[512];
    __shared__ float red[16][16][4];
    {
        float M = -3.0e38f;
#pragma unroll
        for (int i = 0; i < 8; ++i) M = fmaxf(M, stats[(b * 8 + i) * 2]);
        float denom = 0.f, mixv = 0.f;
#pragma unroll
        for (int i = 0; i < 8; ++i) {
            float w = expf(stats[(b * 8 + i) * 2] - M);
            denom += stats[(b * 8 + i) * 2 + 1] * w;
            mixv += mixp[((size_t)b * 8 + i) * E_ + t] * w;
        }
        cat[t] = mixv / denom;
        cat[256 + t] = h[b * H_ + t];
    }
    __syncthreads();
    int ocol = t & 15, ks = t >> 4;
    int o4 = oc * 64 + ocol * 4;
    float a0 = 0.f, a1 = 0.f, a2 = 0.f, a3 = 0.f;
    const float* wp = &WT_attn[(size_t)(ks * 32) * 256 + o4];
#pragma unroll 8
    for (int k = 0; k < 32; ++k) {
        float4 w = *(const float4*)&wp[(size_t)k * 256];
        float cv = cat[ks * 32 + k];
        a0 += cv * w.x; a1 += cv * w.y; a2 += cv * w.z; a3 += cv * w.w;
    }
    red[ks][ocol][0] = a0; red[ks][ocol][1] = a1; red[ks][ocol][2] = a2; red[ks][ocol][3] = a3;
    __syncthreads();
    if (t < 64) {
        int oc2 = t >> 2, j = t & 3;
        float s = 0.f;
#pragma unroll
        for (int k2 = 0; k2 < 16; ++k2) s += red[k2][oc2][j];
        int o = oc * 64 + t;
        aout[b * E_ + o] = tanhf(s + b_attn[o]);
    }
}

// ---------------- post2: ocontrib (split-K over c), one matrix per blockIdx.y ----------------
__global__ __launch_bounds__(256) void k_post2(
    const float* __restrict__ aout, const float* __restrict__ wpk,
    float* __restrict__ cr0, float* __restrict__ fullv, float* __restrict__ cr2) {
    int b = blockIdx.x, m = blockIdx.y, t = threadIdx.x;
    __shared__ float os[256];
    __shared__ float red[4][64][4];
    os[t] = aout[b * E_ + t];
    __syncthreads();
    int ocol = t & 63, cs = t >> 6;
    int o4 = ocol * 4;
    const float* wp = &wpk[(size_t)m * 65536 + (size_t)(cs * 64) * 256 + o4];
    float a0 = 0.f, a1 = 0.f, a2 = 0.f, a3 = 0.f;
#pragma unroll 8
    for (int c = 0; c < 64; ++c) {
        float4 w = *(const float4*)&wp[(size_t)c * 256];
        float v = os[cs * 64 + c];
        a0 += v * w.x; a1 += v * w.y; a2 += v * w.z; a3 += v * w.w;
    }
    red[cs][ocol][0] = a0; red[cs][ocol][1] = a1; red[cs][ocol][2] = a2; red[cs][ocol][3] = a3;
    __syncthreads();
    int oc2 = t >> 2, j = t & 3;
    float s = red[0][oc2][j] + red[1][oc2][j] + red[2][oc2][j] + red[3][oc2][j];
    float* dst = (m == 0) ? cr0 : (m == 1) ? fullv : cr2;
    dst[b * E_ + t] = s;
}

// ---------------- conv as bf16 MFMA GEMM, 64l x 256o per block, fused heads ----------------
template <bool FUSE_HEADS, bool WRITE_OUT>
__global__ __launch_bounds__(256) void k_conv_mfma(
    const unsigned short* __restrict__ encbf, const unsigned short* __restrict__ bp,
    const float* __restrict__ bias, const float* __restrict__ fullv,
    const float* __restrict__ cr0, const float* __restrict__ cr2,
    unsigned short* __restrict__ enc_out,
    const float* __restrict__ w_e1, const float* __restrict__ b_e1,
    const float* __restrict__ w_e2, const float* __restrict__ b_e2,
    float* __restrict__ o1, float* __restrict__ o2) {
    const int b = blockIdx.y, l0 = blockIdx.x * 64;
    const int t = threadIdx.x, lane = t & 63, wid = t >> 6;
    __shared__ unsigned short As[66 * 256];
    __shared__ float hsum[2][4][64];

    for (int u = t; u < 66 * 32; u += 256) {
        int row = u >> 5, cu = u & 31;
        int l = l0 - 1 + row;
        uint4 v = {0u, 0u, 0u, 0u};
        if (l >= 0 && l < L_) v = *(const uint4*)&encbf[((size_t)b * L_ + l) * E_ + cu * 8];
        *(uint4*)&As[row * 256 + ((cu ^ (row & 7)) << 3)] = v;
    }
    __syncthreads();

    const int wo4 = wid * 4;
    f32x4 zero = {0.f, 0.f, 0.f, 0.f};
    f32x4 acc[4][4];
#pragma unroll
    for (int i = 0; i < 4; ++i)
#pragma unroll
        for (int j = 0; j < 4; ++j) acc[i][j] = zero;
    const int arow = lane & 15, agrp = lane >> 4;

#pragma unroll 2
    for (int kc = 0; kc < 24; ++kc) {
        const int k = kc >> 3;
        const int g = ((kc & 7) << 2) + agrp;
        bf16x8 a[4], bv[4];
#pragma unroll
        for (int mi = 0; mi < 4; ++mi) {
            int r = mi * 16 + arow + k;
            a[mi] = *(const bf16x8*)&As[r * 256 + ((g ^ (r & 7)) << 3)];
        }
#pragma unroll
        for (int ni = 0; ni < 4; ++ni)
            bv[ni] = *(const bf16x8*)&bp[(((size_t)(wo4 + ni) * 24 + kc) * 64 + lane) * 8];
#pragma unroll
        for (int mi = 0; mi < 4; ++mi)
#pragma unroll
            for (int ni = 0; ni < 4; ++ni)
                acc[mi][ni] = __builtin_amdgcn_mfma_f32_16x16x32_bf16(a[mi], bv[ni], acc[mi][ni], 0, 0, 0);
    }

    float biasv[4], c0v[4], c2v[4], we1[4], we2[4];
#pragma unroll
    for (int ni = 0; ni < 4; ++ni) {
        int o = (wo4 + ni) * 16 + (lane & 15);
        biasv[ni] = bias[o] + fullv[b * E_ + o];
        c0v[ni] = cr0[b * E_ + o];
        c2v[ni] = cr2[b * E_ + o];
        if (FUSE_HEADS) { we1[ni] = w_e1[o]; we2[ni] = w_e2[o]; }
    }
    __syncthreads();

#pragma unroll
    for (int mi = 0; mi < 4; ++mi) {
#pragma unroll
        for (int r = 0; r < 4; ++r) {
            int lloc = mi * 16 + agrp * 4 + r;
            int lrow = l0 + lloc;
            float p1 = 0.f, p2 = 0.f;
#pragma unroll
            for (int ni = 0; ni < 4; ++ni) {
                float vv = acc[mi][ni][r] + biasv[ni];
                if (lrow == 0) vv -= c0v[ni];
                if (lrow == L_ - 1) vv -= c2v[ni];
                if (WRITE_OUT) As[lloc * 256 + (wo4 + ni) * 16 + (lane & 15)] = f2bf(vv);
                if (FUSE_HEADS) {
                    float gv = geluf_(vv);
                    p1 += gv * we1[ni];
                    p2 += gv * we2[ni];
                }
            }
            if (FUSE_HEADS) {
#pragma unroll
                for (int off = 1; off < 16; off <<= 1) {
                    p1 += __shfl_xor(p1, off);
                    p2 += __shfl_xor(p2, off);
                }
                if ((lane & 15) == 0) {
                    hsum[0][wid][lloc] = p1;
                    hsum[1][wid][lloc] = p2;
                }
            }
        }
    }
    __syncthreads();
    if (WRITE_OUT) {
        for (int u = t; u < 64 * 32; u += 256) {
            int row = u >> 5, cu = u & 31;
            *(uint4*)&enc_out[((size_t)b * L_ + l0 + row) * E_ + cu * 8] = *(const uint4*)&As[row * 256 + cu * 8];
        }
    }
    if (FUSE_HEADS && t < 128) {
        int hh = t >> 6, row = t & 63;
        float s = hsum[hh][0][row] + hsum[hh][1][row] + hsum[hh][2][row] + hsum[hh][3][row];
        float* dst = hh ? o2 : o1;
        const float* bb = hh ? b_e2 : b_e1;
        dst[(size_t)b * L_ + l0 + row] = s + bb[0];
    }
}

// ---------------- relation head: MFMA gelu(enc) @ W_rel^T, masked max ----------------
__global__ __launch_bounds__(256) void k_relmax_mfma(
    const unsigned short* __restrict__ encbf, const unsigned short* __restrict__ wp,
    const float* __restrict__ b_rel, const int* __restrict__ T,
    float* __restrict__ pmax) {
    const int b = blockIdx.y, l0 = blockIdx.x * 64;
    const int t = threadIdx.x, lane = t & 63, wid = t >> 6;
    __shared__ unsigned short As[64 * 256];
    __shared__ int Tm[64];
    __shared__ float pm[4][64];

    if (t < 64) Tm[t] = T[b * L_ + l0 + t];
    for (int u = t; u < 64 * 32; u += 256) {
        int row = u >> 5, cu = u & 31;
        uint4 q = *(const uint4*)&encbf[((size_t)b * L_ + l0 + row) * E_ + cu * 8];
        unsigned short s[8];
        unsigned qa[4] = {q.x, q.y, q.z, q.w};
#pragma unroll
        for (int j = 0; j < 4; ++j) {
            s[2 * j] = f2bf(geluf_(bf2f(qa[j] & 0xffffu)));
            s[2 * j + 1] = f2bf(geluf_(bf2f(qa[j] >> 16)));
        }
        uint4 p;
        p.x = (unsigned)s[0] | ((unsigned)s[1] << 16);
        p.y = (unsigned)s[2] | ((unsigned)s[3] << 16);
        p.z = (unsigned)s[4] | ((unsigned)s[5] << 16);
        p.w = (unsigned)s[6] | ((unsigned)s[7] << 16);
        *(uint4*)&As[row * 256 + ((cu ^ (row & 7)) << 3)] = p;
    }
    __syncthreads();

    f32x4 zero = {0.f, 0.f, 0.f, 0.f};
    f32x4 acc[4] = {zero, zero, zero, zero};
    const int arow = wid * 16 + (lane & 15);
    const int agrp = lane >> 4;
#pragma unroll 2
    for (int kc = 0; kc < 8; ++kc) {
        int g = (kc << 2) + agrp;
        bf16x8 a0 = *(const bf16x8*)&As[arow * 256 + ((g ^ (arow & 7)) << 3)];
#pragma unroll
        for (int ni = 0; ni < 4; ++ni) {
            bf16x8 bv = *(const bf16x8*)&wp[(((size_t)ni * 8 + kc) * 64 + lane) * 8];
            acc[ni] = __builtin_amdgcn_mfma_f32_16x16x32_bf16(a0, bv, acc[ni], 0, 0, 0);
        }
    }

    const int lloc_base = wid * 16 + ((lane >> 4) << 2);
#pragma unroll
    for (int ni = 0; ni < 4; ++ni) {
        int r = ni * 16 + (lane & 15);
        float brel = (r < R_) ? b_rel[r] : 0.f;
        float v = -3.0e38f;
#pragma unroll
        for (int rg = 0; rg < 4; ++rg) {
            float logit = acc[ni][rg] + brel;
            float pen = (Tm[lloc_base + rg] > 0) ? 0.f : NEG_;
            v = fmaxf(v, logit - pen);
        }
        v = fmaxf(v, __shfl_xor(v, 16));
        v = fmaxf(v, __shfl_xor(v, 32));
        if (lane < 16) pm[wid][ni * 16 + lane] = v;
    }
    __syncthreads();
    if (t < 64) {
        float m = fmaxf(fmaxf(pm[0][t], pm[1][t]), fmaxf(pm[2][t], pm[3][t]));
        pmax[((size_t)b * 8 + blockIdx.x) * 64 + t] = m;
    }
}

__global__ void k_relmax_red(const float* __restrict__ pmax, float* __restrict__ t2rel) {
    int b = blockIdx.x, r = threadIdx.x;
    if (r >= R_) return;
    float m = -3.0e38f;
    for (int ch = 0; ch < 8; ++ch) m = fmaxf(m, pmax[((size_t)b * 8 + ch) * 64 + r]);
    t2rel[b * R_ + r] = m;
}

// ---------------- driver ----------------
extern "C" void kernel_launch(void* const* d_in, const int* in_sizes, int n_in,
                              void* d_out, int out_size, void* d_ws, size_t ws_size,
                              hipStream_t stream) {
    const float* encoder_o = (const float*)d_in[0];
    const float* h0 = (const float*)d_in[1];
    const float* c0 = (const float*)d_in[2];
    const float* sos_emb = (const float*)d_in[3];
    const float* rel_emb = (const float*)d_in[4];
    const float* W_ih = (const float*)d_in[5];
    const float* W_hh = (const float*)d_in[6];
    const float* b_ih = (const float*)d_in[7];
    const float* b_hh = (const float*)d_in[8];
    const float* W_attn = (const float*)d_in[9];
    const float* b_attn = (const float*)d_in[10];
    const float* conv_rel_w = (const float*)d_in[11];
    const float* conv_rel_b = (const float*)d_in[12];
    const float* conv_ent_w = (const float*)d_in[13];
    const float* conv_ent_b = (const float*)d_in[14];
    const float* W_rel = (const float*)d_in[15];
    const float* b_rel = (const float*)d_in[16];
    const float* w_e1 = (const float*)d_in[17];
    const float* b_e1 = (const float*)d_in[18];
    const float* w_e2 = (const float*)d_in[19];
    const float* b_e2 = (const float*)d_in[20];
    const int* T = (const int*)d_in[21];
    const int* R_in = (const int*)d_in[22];
    const int* S_K1 = (const int*)d_in[23];
    const int* S_K2 = (const int*)d_in[24];

    float* out = (float*)d_out;
    float* t1e1 = out;
    float* t1e2 = out + 32768;
    float* t2rel = out + 65536;
    float* t3e1 = out + 68736;
    float* t3e2 = out + 101504;

    float* ws = (float*)d_ws;
    size_t off = 0;
    unsigned short* encBF0 = (unsigned short*)(ws + off); off += (size_t)B_ * L_ * E_ / 2;
    unsigned short* encA = (unsigned short*)(ws + off); off += (size_t)B_ * L_ * E_ / 2;
    unsigned short* encB = (unsigned short*)(ws + off); off += (size_t)B_ * L_ * E_ / 2;
    float* gates = ws + off; off += 4 * 65536;
    float* hbuf = ws + off; off += B_ * H_;
    float* cb1 = ws + off; off += B_ * H_;
    float* cb2 = ws + off; off += B_ * H_;
    float* cb3 = ws + off; off += B_ * H_;
    float* mixp = ws + off; off += (size_t)B_ * 8 * E_;
    float* stats = ws + off; off += B_ * 8 * 2;
    float* aoutb = ws + off; off += B_ * E_;
    float* fullv = ws + off; off += B_ * E_;
    float* cr0 = ws + off; off += B_ * E_;
    float* cr2 = ws + off; off += B_ * E_;
    float* pmax = ws + off; off += B_ * 8 * 64;
    float* wpkE = ws + off; off += 3 * 65536;
    float* wpkR = ws + off; off += 3 * 65536;
    float* WTat = ws + off; off += 131072;
    unsigned short* bpE = (unsigned short*)(ws + off); off += 16 * 24 * 64 * 8 / 2;
    unsigned short* bpR = (unsigned short*)(ws + off); off += 16 * 24 * 64 * 8 / 2;
    unsigned short* wpR = (unsigned short*)(ws + off); off += 4 * 8 * 64 * 8 / 2;

    dim3 convGrid(8, B_);
    dim3 attnGrid(8, B_);
    dim3 rmGrid(8, B_);
    dim3 lstmGrid(16, 2, 2);
    dim3 p1Grid(B_, 4);
    dim3 p2Grid(B_, 3);

    // one-time packs
    k_tobf16<<<(B_ * L_ * E_) / 1024, 256, 0, stream>>>(encoder_o, encBF0);
    k_packB<<<96, 256, 0, stream>>>(conv_ent_w, bpE);
    k_packB<<<96, 256, 0, stream>>>(conv_rel_w, bpR);
    k_packW<<<8, 256, 0, stream>>>(W_rel, wpR);
    k_packC<<<256, 256, 0, stream>>>(conv_ent_w, wpkE);
    k_packC<<<256, 256, 0, stream>>>(conv_rel_w, wpkR);
    k_packWT<<<512, 256, 0, stream>>>(W_attn, WTat);

    // ---- step 1 ----
    k_lstm_gemm<0><<<lstmGrid, 256, 0, stream>>>(sos_emb, nullptr, nullptr, nullptr, nullptr,
                                                 h0, W_ih, W_hh, gates);
    k_attn_part<<<attnGrid, 256, 0, stream>>>(gates, b_ih, b_hh, c0, cb1, hbuf, encBF0, mixp, stats);
    k_post1<<<p1Grid, 256, 0, stream>>>(mixp, stats, hbuf, WTat, b_attn, aoutb);
    k_post2<<<p2Grid, 256, 0, stream>>>(aoutb, wpkE, cr0, fullv, cr2);
    k_conv_mfma<true, true><<<convGrid, 256, 0, stream>>>(encBF0, bpE, conv_ent_b, fullv, cr0, cr2,
                                                          encA, w_e1, b_e1, w_e2, b_e2, t1e1, t1e2);

    // ---- step 2 ----
    k_lstm_gemm<1><<<lstmGrid, 256, 0, stream>>>(nullptr, encA, S_K1, S_K2, nullptr,
                                                 hbuf, W_ih, W_hh, gates);
    k_attn_part<<<attnGrid, 256, 0, stream>>>(gates, b_ih, b_hh, cb1, cb2, hbuf, encA, mixp, stats);
    k_post1<<<p1Grid, 256, 0, stream>>>(mixp, stats, hbuf, WTat, b_attn, aoutb);
    k_post2<<<p2Grid, 256, 0, stream>>>(aoutb, wpkR, cr0, fullv, cr2);
    k_conv_mfma<false, true><<<convGrid, 256, 0, stream>>>(encA, bpR, conv_rel_b, fullv, cr0, cr2,
                                                           encB, nullptr, nullptr, nullptr, nullptr,
                                                           nullptr, nullptr);
    k_relmax_mfma<<<rmGrid, 256, 0, stream>>>(encB, wpR, b_rel, T, pmax);
    k_relmax_red<<<B_, 64, 0, stream>>>(pmax, t2rel);

    // ---- step 3 ----
    k_lstm_gemm<2><<<lstmGrid, 256, 0, stream>>>(rel_emb, nullptr, nullptr, nullptr, R_in,
                                                 hbuf, W_ih, W_hh, gates);
    k_attn_part<<<attnGrid, 256, 0, stream>>>(gates, b_ih, b_hh, cb2, cb3, hbuf, encB, mixp, stats);
    k_post1<<<p1Grid, 256, 0, stream>>>(mixp, stats, hbuf, WTat, b_attn, aoutb);
    k_post2<<<p2Grid, 256, 0, stream>>>(aoutb, wpkE, cr0, fullv, cr2);
    k_conv_mfma<true, false><<<convGrid, 256, 0, stream>>>(encB, bpE, conv_ent_b, fullv, cr0, cr2,
                                                           nullptr, w_e1, b_e1, w_e2, b_e2, t3e1, t3e2);
}

// Round 5
// 190.543 us; speedup vs baseline: 12.6119x; 1.1933x over previous
//
#include <hip/hip_runtime.h>
#include <math.h>

#define B_ 64
#define L_ 512
#define E_ 256
#define H_ 256
#define R_ 50
#define NEG_ 1.0e10f

typedef __bf16 bf16x8 __attribute__((ext_vector_type(8)));
typedef float f32x4 __attribute__((ext_vector_type(4)));

__device__ __forceinline__ float sigmoidf_(float x) { return 1.0f / (1.0f + expf(-x)); }
__device__ __forceinline__ float geluf_(float x) { return 0.5f * x * (1.0f + erff(x * 0.7071067811865476f)); }
__device__ __forceinline__ unsigned short f2bf(float x) {
    unsigned u = __float_as_uint(x);
    return (unsigned short)((u + 0x7fffu + ((u >> 16) & 1u)) >> 16);
}
__device__ __forceinline__ float bf2f(unsigned u) { return __uint_as_float(u << 16); }

// ---------------- fused one-time converts / packs (single launch) ----------------
__global__ void k_packs(const float* __restrict__ encoder_o, unsigned short* __restrict__ encBF0,
                        const float* __restrict__ conv_ent_w, const float* __restrict__ conv_rel_w,
                        unsigned short* __restrict__ bpE, unsigned short* __restrict__ bpR,
                        const float* __restrict__ W_rel, unsigned short* __restrict__ wpR,
                        float* __restrict__ wpkE, float* __restrict__ wpkR,
                        const float* __restrict__ W_attn, float* __restrict__ WTat) {
    const int blk = blockIdx.x, t = threadIdx.x;
    if (blk < 8192) {
        // encoder_o -> bf16
        size_t idx = (size_t)blk * 256 + t;
        float4 v = *(const float4*)&encoder_o[idx * 4];
        uint2 p;
        p.x = (unsigned)f2bf(v.x) | ((unsigned)f2bf(v.y) << 16);
        p.y = (unsigned)f2bf(v.z) | ((unsigned)f2bf(v.w) << 16);
        *(uint2*)&encBF0[idx * 4] = p;
    } else if (blk < 8384) {
        // conv weights (c<256) -> MFMA B-frag order: bp[of 16][kc 24][lane 64][8]
        const float* w = (blk < 8288) ? conv_ent_w : conv_rel_w;
        unsigned short* bp = (blk < 8288) ? bpE : bpR;
        int idx = (blk - ((blk < 8288) ? 8192 : 8288)) * 256 + t;
        int l = idx & 63, kc = (idx >> 6) % 24, of = idx / (24 * 64);
        int o = of * 16 + (l & 15);
        int k = kc >> 3;
        int cb = ((kc & 7) << 5) + ((l >> 4) << 3);
        unsigned short v[8];
#pragma unroll
        for (int j = 0; j < 8; ++j) v[j] = f2bf(w[(size_t)o * 1536 + (size_t)(cb + j) * 3 + k]);
        unsigned int* dst = (unsigned int*)&bp[(size_t)idx * 8];
#pragma unroll
        for (int j = 0; j < 4; ++j) dst[j] = (unsigned int)v[2 * j] | ((unsigned int)v[2 * j + 1] << 16);
    } else if (blk < 8392) {
        // W_rel (50x256 -> pad 64): wp[of 4][kc 8][lane 64][8]
        int idx = (blk - 8384) * 256 + t;
        int l = idx & 63, kc = (idx >> 6) & 7, of = idx / (8 * 64);
        int r = of * 16 + (l & 15);
        int k = kc * 32 + ((l >> 4) << 3);
        unsigned short v[8];
#pragma unroll
        for (int j = 0; j < 8; ++j) v[j] = (r < R_) ? f2bf(W_rel[(size_t)r * E_ + k + j]) : 0;
        unsigned int* dst = (unsigned int*)&wpR[(size_t)idx * 8];
#pragma unroll
        for (int j = 0; j < 4; ++j) dst[j] = (unsigned int)v[2 * j] | ((unsigned int)v[2 * j + 1] << 16);
    } else if (blk < 8904) {
        // ocontrib weights (c=256..511): wpk[0]=w0, wpk[1]=w0+w1+w2, wpk[2]=w2
        const float* w = (blk < 8648) ? conv_ent_w : conv_rel_w;
        float* wpk = (blk < 8648) ? wpkE : wpkR;
        int idx = (blk - ((blk < 8648) ? 8392 : 8648)) * 256 + t;
        int o = idx >> 8, c = idx & 255;
        const float* p = &w[(size_t)o * 1536 + 768 + c * 3];
        float w0 = p[0], w1 = p[1], w2 = p[2];
        wpk[c * 256 + o] = w0;
        wpk[65536 + c * 256 + o] = w0 + w1 + w2;
        wpk[131072 + c * 256 + o] = w2;
    } else {
        // transpose W_attn (256 x 512) -> WT[k][o]
        int idx = (blk - 8904) * 256 + t;
        int o = idx >> 9, k = idx & 511;
        WTat[k * 256 + o] = W_attn[idx];
    }
}

// ---------------- LSTM gemm, split-K: grid (16, 2, 2) ----------------
template <int MODE>
__global__ __launch_bounds__(256) void k_lstm_gemm(
    const float* __restrict__ xsrc_f, const unsigned short* __restrict__ encg,
    const int* __restrict__ i1, const int* __restrict__ i2, const int* __restrict__ rin,
    const float* __restrict__ hprev,
    const float* __restrict__ W_ih, const float* __restrict__ W_hh,
    float* __restrict__ gates) {
    const int g0 = blockIdx.x * 64;
    const int half = blockIdx.y, z = blockIdx.z;
    const int t = threadIdx.x, tx = t & 15, ty = t >> 4;
    __shared__ float Xs[64][68];
    __shared__ float Wt[64][68];
    const float* Wsrc = half ? W_hh : W_ih;
    float acc[4][4] = {{0.f}};
    for (int kb = z * 128; kb < z * 128 + 128; kb += 64) {
        __syncthreads();
#pragma unroll
        for (int i = 0; i < 4; ++i) {
            int idx = i * 256 + t;
            int row = idx >> 4, kk = (idx & 15) << 2;
            float4 xv;
            if (half) {
                xv = *(const float4*)&hprev[row * 256 + kb + kk];
            } else if (MODE == 0) {
                xv = *(const float4*)&xsrc_f[kb + kk];
            } else if (MODE == 2) {
                xv = *(const float4*)&xsrc_f[(size_t)rin[row] * 256 + kb + kk];
            } else {
                const unsigned short* p1 = &encg[((size_t)row * L_ + i1[row]) * E_ + kb + kk];
                const unsigned short* p2 = &encg[((size_t)row * L_ + i2[row]) * E_ + kb + kk];
                uint2 a = *(const uint2*)p1, b2 = *(const uint2*)p2;
                xv.x = bf2f(a.x & 0xffffu) + bf2f(b2.x & 0xffffu);
                xv.y = bf2f(a.x >> 16) + bf2f(b2.x >> 16);
                xv.z = bf2f(a.y & 0xffffu) + bf2f(b2.y & 0xffffu);
                xv.w = bf2f(a.y >> 16) + bf2f(b2.y >> 16);
            }
            *(float4*)&Xs[row][kk] = xv;
            *(float4*)&Wt[row][kk] = *(const float4*)&Wsrc[(size_t)(g0 + row) * 256 + kb + kk];
        }
        __syncthreads();
#pragma unroll
        for (int kk = 0; kk < 64; kk += 4) {
            float4 xv[4], wv[4];
#pragma unroll
            for (int i = 0; i < 4; ++i) xv[i] = *(const float4*)&Xs[ty * 4 + i][kk];
#pragma unroll
            for (int j = 0; j < 4; ++j) wv[j] = *(const float4*)&Wt[tx * 4 + j][kk];
#pragma unroll
            for (int i = 0; i < 4; ++i)
#pragma unroll
                for (int j = 0; j < 4; ++j)
                    acc[i][j] += xv[i].x * wv[j].x + xv[i].y * wv[j].y + xv[i].z * wv[j].z + xv[i].w * wv[j].w;
        }
    }
    const int seg = half * 2 + z;
#pragma unroll
    for (int i = 0; i < 4; ++i)
#pragma unroll
        for (int j = 0; j < 4; ++j)
            gates[(size_t)seg * 65536 + (size_t)(ty * 4 + i) * 1024 + g0 + tx * 4 + j] = acc[i][j];
}

// ---------------- attention partial (64-l chunks) with fused LSTM finish ----------------
__global__ __launch_bounds__(256) void k_attn_part(
    const float* __restrict__ gates, const float* __restrict__ b_ih, const float* __restrict__ b_hh,
    const float* __restrict__ c_in, float* __restrict__ c_out, float* __restrict__ h_out,
    const unsigned short* __restrict__ encbf,
    float* __restrict__ mixp, float* __restrict__ stats) {
    int b = blockIdx.y, ch = blockIdx.x, t = threadIdx.x;
    __shared__ float hs[E_];
    __shared__ float scp[64][4];
    __shared__ float sc[64];
    {
        size_t ba = (size_t)b * 1024;
        float g4[4];
#pragma unroll
        for (int g = 0; g < 4; ++g) {
            float acc = b_ih[g * 256 + t] + b_hh[g * 256 + t];
#pragma unroll
            for (int seg = 0; seg < 4; ++seg) acc += gates[(size_t)seg * 65536 + ba + g * 256 + t];
            g4[g] = acc;
        }
        float c = sigmoidf_(g4[1]) * c_in[b * H_ + t] + sigmoidf_(g4[0]) * tanhf(g4[2]);
        float hv = sigmoidf_(g4[3]) * tanhf(c);
        hs[t] = hv;
        if (ch == 0) { h_out[b * H_ + t] = hv; c_out[b * H_ + t] = c; }
    }
    __syncthreads();
    {
        int row = t >> 2, es = t & 3;
        const uint4* p = (const uint4*)&encbf[((size_t)b * L_ + ch * 64 + row) * E_ + es * 64];
        float acc = 0.f;
#pragma unroll
        for (int k = 0; k < 8; ++k) {
            uint4 q = p[k];
            int e0 = es * 64 + k * 8;
            acc += bf2f(q.x & 0xffffu) * hs[e0] + bf2f(q.x >> 16) * hs[e0 + 1]
                 + bf2f(q.y & 0xffffu) * hs[e0 + 2] + bf2f(q.y >> 16) * hs[e0 + 3]
                 + bf2f(q.z & 0xffffu) * hs[e0 + 4] + bf2f(q.z >> 16) * hs[e0 + 5]
                 + bf2f(q.w & 0xffffu) * hs[e0 + 6] + bf2f(q.w >> 16) * hs[e0 + 7];
        }
        scp[row][es] = acc;
    }
    __syncthreads();
    if (t < 64) {
        float v = scp[t][0] + scp[t][1] + scp[t][2] + scp[t][3];
        float m = v;
#pragma unroll
        for (int off = 32; off; off >>= 1) m = fmaxf(m, __shfl_xor(m, off));
        float ev = expf(v - m);
        float s = ev;
#pragma unroll
        for (int off = 32; off; off >>= 1) s += __shfl_xor(s, off);
        sc[t] = ev;
        if (t == 0) {
            stats[((size_t)b * 8 + ch) * 2] = m;
            stats[((size_t)b * 8 + ch) * 2 + 1] = s;
        }
    }
    __syncthreads();
    float acc = 0.f;
    const unsigned short* base = &encbf[((size_t)b * L_ + ch * 64) * E_ + t];
#pragma unroll 8
    for (int l = 0; l < 64; ++l) acc += sc[l] * bf2f((unsigned)base[(size_t)l * E_]);
    mixp[((size_t)b * 8 + ch) * E_ + t] = acc;
}

// ---------------- post1: combine + attn-out GEMV (split-K) ----------------
__global__ __launch_bounds__(256) void k_post1(
    const float* __restrict__ mixp, const float* __restrict__ stats,
    const float* __restrict__ h, const float* __restrict__ WT_attn,
    const float* __restrict__ b_attn, float* __restrict__ aout) {
    int b = blockIdx.x, oc = blockIdx.y, t = threadIdx.x;
    __shared__ float cat[512];
    __shared__ float red[16][16][4];
    {
        float M = -3.0e38f;
#pragma unroll
        for (int i = 0; i < 8; ++i) M = fmaxf(M, stats[(b * 8 + i) * 2]);
        float denom = 0.f, mixv = 0.f;
#pragma unroll
        for (int i = 0; i < 8; ++i) {
            float w = expf(stats[(b * 8 + i) * 2] - M);
            denom += stats[(b * 8 + i) * 2 + 1] * w;
            mixv += mixp[((size_t)b * 8 + i) * E_ + t] * w;
        }
        cat[t] = mixv / denom;
        cat[256 + t] = h[b * H_ + t];
    }
    __syncthreads();
    int ocol = t & 15, ks = t >> 4;
    int o4 = oc * 64 + ocol * 4;
    float a0 = 0.f, a1 = 0.f, a2 = 0.f, a3 = 0.f;
    const float* wp = &WT_attn[(size_t)(ks * 32) * 256 + o4];
#pragma unroll 8
    for (int k = 0; k < 32; ++k) {
        float4 w = *(const float4*)&wp[(size_t)k * 256];
        float cv = cat[ks * 32 + k];
        a0 += cv * w.x; a1 += cv * w.y; a2 += cv * w.z; a3 += cv * w.w;
    }
    red[ks][ocol][0] = a0; red[ks][ocol][1] = a1; red[ks][ocol][2] = a2; red[ks][ocol][3] = a3;
    __syncthreads();
    if (t < 64) {
        int oc2 = t >> 2, j = t & 3;
        float s = 0.f;
#pragma unroll
        for (int k2 = 0; k2 < 16; ++k2) s += red[k2][oc2][j];
        int o = oc * 64 + t;
        aout[b * E_ + o] = tanhf(s + b_attn[o]);
    }
}

// ---------------- post2: ocontrib (split-K over c) ----------------
__global__ __launch_bounds__(256) void k_post2(
    const float* __restrict__ aout, const float* __restrict__ wpk,
    float* __restrict__ cr0, float* __restrict__ fullv, float* __restrict__ cr2) {
    int b = blockIdx.x, m = blockIdx.y, t = threadIdx.x;
    __shared__ float os[256];
    __shared__ float red[4][64][4];
    os[t] = aout[b * E_ + t];
    __syncthreads();
    int ocol = t & 63, cs = t >> 6;
    int o4 = ocol * 4;
    const float* wp = &wpk[(size_t)m * 65536 + (size_t)(cs * 64) * 256 + o4];
    float a0 = 0.f, a1 = 0.f, a2 = 0.f, a3 = 0.f;
#pragma unroll 8
    for (int c = 0; c < 64; ++c) {
        float4 w = *(const float4*)&wp[(size_t)c * 256];
        float v = os[cs * 64 + c];
        a0 += v * w.x; a1 += v * w.y; a2 += v * w.z; a3 += v * w.w;
    }
    red[cs][ocol][0] = a0; red[cs][ocol][1] = a1; red[cs][ocol][2] = a2; red[cs][ocol][3] = a3;
    __syncthreads();
    int oc2 = t >> 2, j = t & 3;
    float s = red[0][oc2][j] + red[1][oc2][j] + red[2][oc2][j] + red[3][oc2][j];
    float* dst = (m == 0) ? cr0 : (m == 1) ? fullv : cr2;
    dst[b * E_ + t] = s;
}

// ---------------- conv as bf16 MFMA GEMM: 64l x 256o per block, 8 waves, B-prefetch ----------------
template <bool FUSE_HEADS, bool WRITE_OUT>
__global__ __launch_bounds__(512, 4) void k_conv_mfma(
    const unsigned short* __restrict__ encbf, const unsigned short* __restrict__ bp,
    const float* __restrict__ bias, const float* __restrict__ fullv,
    const float* __restrict__ cr0, const float* __restrict__ cr2,
    unsigned short* __restrict__ enc_out,
    const float* __restrict__ w_e1, const float* __restrict__ b_e1,
    const float* __restrict__ w_e2, const float* __restrict__ b_e2,
    float* __restrict__ o1, float* __restrict__ o2) {
    const int b = blockIdx.y, l0 = blockIdx.x * 64;
    const int t = threadIdx.x, lane = t & 63, wid = t >> 6;
    __shared__ unsigned short As[66 * 256];
    __shared__ float hsum[2][8][64];

    // stage A (bf16 copy, XOR-swizzled, zero halo)
    for (int u = t; u < 66 * 32; u += 512) {
        int row = u >> 5, cu = u & 31;
        int l = l0 - 1 + row;
        uint4 v = {0u, 0u, 0u, 0u};
        if (l >= 0 && l < L_) v = *(const uint4*)&encbf[((size_t)b * L_ + l) * E_ + cu * 8];
        *(uint4*)&As[row * 256 + ((cu ^ (row & 7)) << 3)] = v;
    }
    __syncthreads();

    const int wo2 = wid * 2;                 // this wave's 2 o-frags (32 o)
    f32x4 zero = {0.f, 0.f, 0.f, 0.f};
    f32x4 acc[4][2];
#pragma unroll
    for (int i = 0; i < 4; ++i) { acc[i][0] = zero; acc[i][1] = zero; }
    const int arow = lane & 15, agrp = lane >> 4;
    const unsigned short* bp0 = &bp[((size_t)wo2 * 24 * 64 + lane) * 8];
    const unsigned short* bp1 = &bp[((size_t)(wo2 + 1) * 24 * 64 + lane) * 8];

    bf16x8 bn0 = *(const bf16x8*)bp0;
    bf16x8 bn1 = *(const bf16x8*)bp1;
#pragma unroll 4
    for (int kc = 0; kc < 24; ++kc) {
        bf16x8 b0 = bn0, b1 = bn1;
        if (kc < 23) {
            bn0 = *(const bf16x8*)&bp0[(size_t)(kc + 1) * 512];
            bn1 = *(const bf16x8*)&bp1[(size_t)(kc + 1) * 512];
        }
        const int k = kc >> 3;
        const int g = ((kc & 7) << 2) + agrp;
        bf16x8 a[4];
#pragma unroll
        for (int mi = 0; mi < 4; ++mi) {
            int r = mi * 16 + arow + k;
            a[mi] = *(const bf16x8*)&As[r * 256 + ((g ^ (r & 7)) << 3)];
        }
#pragma unroll
        for (int mi = 0; mi < 4; ++mi) {
            acc[mi][0] = __builtin_amdgcn_mfma_f32_16x16x32_bf16(a[mi], b0, acc[mi][0], 0, 0, 0);
            acc[mi][1] = __builtin_amdgcn_mfma_f32_16x16x32_bf16(a[mi], b1, acc[mi][1], 0, 0, 0);
        }
    }

    float biasv[2], c0v[2], c2v[2], we1v[2], we2v[2];
#pragma unroll
    for (int ni = 0; ni < 2; ++ni) {
        int o = (wo2 + ni) * 16 + (lane & 15);
        biasv[ni] = bias[o] + fullv[b * E_ + o];
        c0v[ni] = cr0[b * E_ + o];
        c2v[ni] = cr2[b * E_ + o];
        if (FUSE_HEADS) { we1v[ni] = w_e1[o]; we2v[ni] = w_e2[o]; }
    }
    __syncthreads();   // done reading As; reuse as output tile

#pragma unroll
    for (int mi = 0; mi < 4; ++mi) {
#pragma unroll
        for (int r = 0; r < 4; ++r) {
            int lloc = mi * 16 + agrp * 4 + r;
            int lrow = l0 + lloc;
            float p1 = 0.f, p2 = 0.f;
#pragma unroll
            for (int ni = 0; ni < 2; ++ni) {
                float vv = acc[mi][ni][r] + biasv[ni];
                if (lrow == 0) vv -= c0v[ni];
                if (lrow == L_ - 1) vv -= c2v[ni];
                if (WRITE_OUT) As[lloc * 256 + (wo2 + ni) * 16 + (lane & 15)] = f2bf(vv);
                if (FUSE_HEADS) {
                    float gv = geluf_(vv);
                    p1 += gv * we1v[ni];
                    p2 += gv * we2v[ni];
                }
            }
            if (FUSE_HEADS) {
#pragma unroll
                for (int off = 1; off < 16; off <<= 1) {
                    p1 += __shfl_xor(p1, off);
                    p2 += __shfl_xor(p2, off);
                }
                if ((lane & 15) == 0) {
                    hsum[0][wid][lloc] = p1;
                    hsum[1][wid][lloc] = p2;
                }
            }
        }
    }
    __syncthreads();
    if (WRITE_OUT) {
        for (int u = t; u < 64 * 32; u += 512) {
            int row = u >> 5, cu = u & 31;
            *(uint4*)&enc_out[((size_t)b * L_ + l0 + row) * E_ + cu * 8] = *(const uint4*)&As[row * 256 + cu * 8];
        }
    }
    if (FUSE_HEADS && t < 128) {
        int hh = t >> 6, row = t & 63;
        float s = 0.f;
#pragma unroll
        for (int w = 0; w < 8; ++w) s += hsum[hh][w][row];
        float* dst = hh ? o2 : o1;
        const float* bb = hh ? b_e2 : b_e1;
        dst[(size_t)b * L_ + l0 + row] = s + bb[0];
    }
}

// ---------------- relation head: MFMA gelu(enc) @ W_rel^T, masked max ----------------
__global__ __launch_bounds__(256) void k_relmax_mfma(
    const unsigned short* __restrict__ encbf, const unsigned short* __restrict__ wp,
    const float* __restrict__ b_rel, const int* __restrict__ T,
    float* __restrict__ pmax) {
    const int b = blockIdx.y, l0 = blockIdx.x * 64;
    const int t = threadIdx.x, lane = t & 63, wid = t >> 6;
    __shared__ unsigned short As[64 * 256];
    __shared__ int Tm[64];
    __shared__ float pm[4][64];

    if (t < 64) Tm[t] = T[b * L_ + l0 + t];
    for (int u = t; u < 64 * 32; u += 256) {
        int row = u >> 5, cu = u & 31;
        uint4 q = *(const uint4*)&encbf[((size_t)b * L_ + l0 + row) * E_ + cu * 8];
        unsigned short s[8];
        unsigned qa[4] = {q.x, q.y, q.z, q.w};
#pragma unroll
        for (int j = 0; j < 4; ++j) {
            s[2 * j] = f2bf(geluf_(bf2f(qa[j] & 0xffffu)));
            s[2 * j + 1] = f2bf(geluf_(bf2f(qa[j] >> 16)));
        }
        uint4 p;
        p.x = (unsigned)s[0] | ((unsigned)s[1] << 16);
        p.y = (unsigned)s[2] | ((unsigned)s[3] << 16);
        p.z = (unsigned)s[4] | ((unsigned)s[5] << 16);
        p.w = (unsigned)s[6] | ((unsigned)s[7] << 16);
        *(uint4*)&As[row * 256 + ((cu ^ (row & 7)) << 3)] = p;
    }
    __syncthreads();

    f32x4 zero = {0.f, 0.f, 0.f, 0.f};
    f32x4 acc[4] = {zero, zero, zero, zero};
    const int arow = wid * 16 + (lane & 15);
    const int agrp = lane >> 4;
#pragma unroll 2
    for (int kc = 0; kc < 8; ++kc) {
        int g = (kc << 2) + agrp;
        bf16x8 a0 = *(const bf16x8*)&As[arow * 256 + ((g ^ (arow & 7)) << 3)];
#pragma unroll
        for (int ni = 0; ni < 4; ++ni) {
            bf16x8 bv = *(const bf16x8*)&wp[(((size_t)ni * 8 + kc) * 64 + lane) * 8];
            acc[ni] = __builtin_amdgcn_mfma_f32_16x16x32_bf16(a0, bv, acc[ni], 0, 0, 0);
        }
    }

    const int lloc_base = wid * 16 + ((lane >> 4) << 2);
#pragma unroll
    for (int ni = 0; ni < 4; ++ni) {
        int r = ni * 16 + (lane & 15);
        float brel = (r < R_) ? b_rel[r] : 0.f;
        float v = -3.0e38f;
#pragma unroll
        for (int rg = 0; rg < 4; ++rg) {
            float logit = acc[ni][rg] + brel;
            float pen = (Tm[lloc_base + rg] > 0) ? 0.f : NEG_;
            v = fmaxf(v, logit - pen);
        }
        v = fmaxf(v, __shfl_xor(v, 16));
        v = fmaxf(v, __shfl_xor(v, 32));
        if (lane < 16) pm[wid][ni * 16 + lane] = v;
    }
    __syncthreads();
    if (t < 64) {
        float m = fmaxf(fmaxf(pm[0][t], pm[1][t]), fmaxf(pm[2][t], pm[3][t]));
        pmax[((size_t)b * 8 + blockIdx.x) * 64 + t] = m;
    }
}

__global__ void k_relmax_red(const float* __restrict__ pmax, float* __restrict__ t2rel) {
    int b = blockIdx.x, r = threadIdx.x;
    if (r >= R_) return;
    float m = -3.0e38f;
    for (int ch = 0; ch < 8; ++ch) m = fmaxf(m, pmax[((size_t)b * 8 + ch) * 64 + r]);
    t2rel[b * R_ + r] = m;
}

// ---------------- driver ----------------
extern "C" void kernel_launch(void* const* d_in, const int* in_sizes, int n_in,
                              void* d_out, int out_size, void* d_ws, size_t ws_size,
                              hipStream_t stream) {
    const float* encoder_o = (const float*)d_in[0];
    const float* h0 = (const float*)d_in[1];
    const float* c0 = (const float*)d_in[2];
    const float* sos_emb = (const float*)d_in[3];
    const float* rel_emb = (const float*)d_in[4];
    const float* W_ih = (const float*)d_in[5];
    const float* W_hh = (const float*)d_in[6];
    const float* b_ih = (const float*)d_in[7];
    const float* b_hh = (const float*)d_in[8];
    const float* W_attn = (const float*)d_in[9];
    const float* b_attn = (const float*)d_in[10];
    const float* conv_rel_w = (const float*)d_in[11];
    const float* conv_rel_b = (const float*)d_in[12];
    const float* conv_ent_w = (const float*)d_in[13];
    const float* conv_ent_b = (const float*)d_in[14];
    const float* W_rel = (const float*)d_in[15];
    const float* b_rel = (const float*)d_in[16];
    const float* w_e1 = (const float*)d_in[17];
    const float* b_e1 = (const float*)d_in[18];
    const float* w_e2 = (const float*)d_in[19];
    const float* b_e2 = (const float*)d_in[20];
    const int* T = (const int*)d_in[21];
    const int* R_in = (const int*)d_in[22];
    const int* S_K1 = (const int*)d_in[23];
    const int* S_K2 = (const int*)d_in[24];

    float* out = (float*)d_out;
    float* t1e1 = out;
    float* t1e2 = out + 32768;
    float* t2rel = out + 65536;
    float* t3e1 = out + 68736;
    float* t3e2 = out + 101504;

    float* ws = (float*)d_ws;
    size_t off = 0;
    unsigned short* encBF0 = (unsigned short*)(ws + off); off += (size_t)B_ * L_ * E_ / 2;
    unsigned short* encA = (unsigned short*)(ws + off); off += (size_t)B_ * L_ * E_ / 2;
    unsigned short* encB = (unsigned short*)(ws + off); off += (size_t)B_ * L_ * E_ / 2;
    float* gates = ws + off; off += 4 * 65536;
    float* hbuf = ws + off; off += B_ * H_;
    float* cb1 = ws + off; off += B_ * H_;
    float* cb2 = ws + off; off += B_ * H_;
    float* cb3 = ws + off; off += B_ * H_;
    float* mixp = ws + off; off += (size_t)B_ * 8 * E_;
    float* stats = ws + off; off += B_ * 8 * 2;
    float* aoutb = ws + off; off += B_ * E_;
    float* fullv = ws + off; off += B_ * E_;
    float* cr0 = ws + off; off += B_ * E_;
    float* cr2 = ws + off; off += B_ * E_;
    float* pmax = ws + off; off += B_ * 8 * 64;
    float* wpkE = ws + off; off += 3 * 65536;
    float* wpkR = ws + off; off += 3 * 65536;
    float* WTat = ws + off; off += 131072;
    unsigned short* bpE = (unsigned short*)(ws + off); off += 16 * 24 * 64 * 8 / 2;
    unsigned short* bpR = (unsigned short*)(ws + off); off += 16 * 24 * 64 * 8 / 2;
    unsigned short* wpR = (unsigned short*)(ws + off); off += 4 * 8 * 64 * 8 / 2;

    dim3 convGrid(8, B_);
    dim3 attnGrid(8, B_);
    dim3 rmGrid(8, B_);
    dim3 lstmGrid(16, 2, 2);
    dim3 p1Grid(B_, 4);
    dim3 p2Grid(B_, 3);

    // one-time packs (single launch)
    k_packs<<<9416, 256, 0, stream>>>(encoder_o, encBF0, conv_ent_w, conv_rel_w,
                                      bpE, bpR, W_rel, wpR, wpkE, wpkR, W_attn, WTat);

    // ---- step 1 ----
    k_lstm_gemm<0><<<lstmGrid, 256, 0, stream>>>(sos_emb, nullptr, nullptr, nullptr, nullptr,
                                                 h0, W_ih, W_hh, gates);
    k_attn_part<<<attnGrid, 256, 0, stream>>>(gates, b_ih, b_hh, c0, cb1, hbuf, encBF0, mixp, stats);
    k_post1<<<p1Grid, 256, 0, stream>>>(mixp, stats, hbuf, WTat, b_attn, aoutb);
    k_post2<<<p2Grid, 256, 0, stream>>>(aoutb, wpkE, cr0, fullv, cr2);
    k_conv_mfma<true, true><<<convGrid, 512, 0, stream>>>(encBF0, bpE, conv_ent_b, fullv, cr0, cr2,
                                                          encA, w_e1, b_e1, w_e2, b_e2, t1e1, t1e2);

    // ---- step 2 ----
    k_lstm_gemm<1><<<lstmGrid, 256, 0, stream>>>(nullptr, encA, S_K1, S_K2, nullptr,
                                                 hbuf, W_ih, W_hh, gates);
    k_attn_part<<<attnGrid, 256, 0, stream>>>(gates, b_ih, b_hh, cb1, cb2, hbuf, encA, mixp, stats);
    k_post1<<<p1Grid, 256, 0, stream>>>(mixp, stats, hbuf, WTat, b_attn, aoutb);
    k_post2<<<p2Grid, 256, 0, stream>>>(aoutb, wpkR, cr0, fullv, cr2);
    k_conv_mfma<false, true><<<convGrid, 512, 0, stream>>>(encA, bpR, conv_rel_b, fullv, cr0, cr2,
                                                           encB, nullptr, nullptr, nullptr, nullptr,
                                                           nullptr, nullptr);
    k_relmax_mfma<<<rmGrid, 256, 0, stream>>>(encB, wpR, b_rel, T, pmax);
    k_relmax_red<<<B_, 64, 0, stream>>>(pmax, t2rel);

    // ---- step 3 ----
    k_lstm_gemm<2><<<lstmGrid, 256, 0, stream>>>(rel_emb, nullptr, nullptr, nullptr, R_in,
                                                 hbuf, W_ih, W_hh, gates);
    k_attn_part<<<attnGrid, 256, 0, stream>>>(gates, b_ih, b_hh, cb2, cb3, hbuf, encB, mixp, stats);
    k_post1<<<p1Grid, 256, 0, stream>>>(mixp, stats, hbuf, WTat, b_attn, aoutb);
    k_post2<<<p2Grid, 256, 0, stream>>>(aoutb, wpkE, cr0, fullv, cr2);
    k_conv_mfma<true, false><<<convGrid, 512, 0, stream>>>(encB, bpE, conv_ent_b, fullv, cr0, cr2,
                                                           nullptr, w_e1, b_e1, w_e2, b_e2, t3e1, t3e2);
}